// Round 1
// baseline (1087.819 us; speedup 1.0000x reference)
//
#include <hip/hip_runtime.h>

// Problem constants
#define Bsz 16
#define Nseq 784
#define DIM 512
#define NH 8
#define KD 64
#define VD 256
#define QKV_OUT 3072   // (2*64+256)*8
#define HV 2048        // NH*VD

typedef __attribute__((ext_vector_type(8))) short short8;
typedef __attribute__((ext_vector_type(4))) float floatx4;

#define LSTR 56   // LDS row stride (bf16 elems): 112B -> 16B aligned, 2-way bank alias only (free)

__device__ __forceinline__ unsigned short f2bf(float f) {
  union { float f; unsigned u; } v; v.f = f;
  unsigned r = v.u + 0x7fffu + ((v.u >> 16) & 1u);
  return (unsigned short)(r >> 16);
}

// ---------------- K0: fp32 -> bf16 convert ----------------
__global__ void cvt4_kernel(const float* __restrict__ src,
                            unsigned short* __restrict__ dst, int n4) {
  int i = blockIdx.x * blockDim.x + threadIdx.x;
  int stride = gridDim.x * blockDim.x;
  for (; i < n4; i += stride) {
    float4 v = ((const float4*)src)[i];
    ushort4 o;
    o.x = f2bf(v.x); o.y = f2bf(v.y); o.z = f2bf(v.z); o.w = f2bf(v.w);
    ((ushort4*)dst)[i] = o;
  }
}

// ---------------- K1: QKV GEMM + BN + scatter q/k/vt ----------------
// A = xb [12544][512] bf16, Bw = wq [3072][512] bf16 (both K-contiguous)
__global__ __launch_bounds__(256, 2) void qkv_gemm_kernel(
    const unsigned short* __restrict__ A,
    const unsigned short* __restrict__ Bw,
    const float* __restrict__ gamma, const float* __restrict__ beta,
    const float* __restrict__ mean,  const float* __restrict__ var,
    unsigned short* __restrict__ qo,   // [B,H,N,64] (pre-scaled by 0.125)
    unsigned short* __restrict__ ko,   // [B,H,N,64]
    unsigned short* __restrict__ vto)  // [B,H,256,N]
{
  const int K = DIM;
  __shared__ unsigned short As[128 * LSTR];
  __shared__ unsigned short Bs[128 * LSTR];
  int tid = threadIdx.x;
  int wave = tid >> 6, lane = tid & 63;
  int quad = lane >> 4, l16 = lane & 15;
  int wm = wave >> 1, wn = wave & 1;
  int m0 = blockIdx.y * 128, n0 = blockIdx.x * 128;

  floatx4 acc[4][4];
  for (int i = 0; i < 4; ++i)
    for (int j = 0; j < 4; ++j) acc[i][j] = (floatx4)0.0f;

  for (int k0 = 0; k0 < K; k0 += 32) {
    __syncthreads();
    for (int r = 0; r < 2; ++r) {
      int idx = r * 256 + tid;          // 0..511
      int row = idx >> 2;               // 0..127
      int c8 = (idx & 3) << 3;          // 0,8,16,24 (bf16 elems)
      *(uint4*)&As[row * LSTR + c8] = *(const uint4*)&A[(size_t)(m0 + row) * K + k0 + c8];
      *(uint4*)&Bs[row * LSTR + c8] = *(const uint4*)&Bw[(size_t)(n0 + row) * K + k0 + c8];
    }
    __syncthreads();
    short8 af[4], bf[4];
    for (int mt = 0; mt < 4; ++mt)
      af[mt] = *(const short8*)&As[(wm * 64 + mt * 16 + l16) * LSTR + quad * 8];
    for (int nt = 0; nt < 4; ++nt)
      bf[nt] = *(const short8*)&Bs[(wn * 64 + nt * 16 + l16) * LSTR + quad * 8];
    for (int mt = 0; mt < 4; ++mt)
      for (int nt = 0; nt < 4; ++nt)
        acc[mt][nt] = __builtin_amdgcn_mfma_f32_16x16x32_bf16(af[mt], bf[nt], acc[mt][nt], 0, 0, 0);
  }

  // epilogue: BN then scatter to q / k / v^T (bf16)
  for (int nt = 0; nt < 4; ++nt) {
    int o = n0 + wn * 64 + nt * 16 + l16;        // output channel
    float sc = gamma[o] * rsqrtf(var[o] + 1e-5f);
    float bb = beta[o] - mean[o] * sc;
    int h = o / 384;
    int j = o - h * 384;
    for (int mt = 0; mt < 4; ++mt) {
      for (int r = 0; r < 4; ++r) {
        int m = m0 + wm * 64 + mt * 16 + quad * 4 + r;   // row in [0,12544)
        int b = m / 784;
        int n = m - b * 784;
        float y = acc[mt][nt][r] * sc + bb;
        if (j < 64) {
          qo[(((size_t)b * NH + h) * Nseq + n) * KD + j] = f2bf(y * 0.125f);
        } else if (j < 128) {
          ko[(((size_t)b * NH + h) * Nseq + n) * KD + (j - 64)] = f2bf(y);
        } else {
          vto[(((size_t)b * NH + h) * VD + (j - 128)) * Nseq + n] = f2bf(y);
        }
      }
    }
  }
}

// ---------------- K2: flash attention + bias + softmax + SiLU ----------------
// grid (13 q-tiles, 128 bh), block 256 (4 waves x 16 q-rows)
__global__ __launch_bounds__(256, 2) void attn_kernel(
    const unsigned short* __restrict__ qb,   // [bh][784][64] (pre-scaled)
    const unsigned short* __restrict__ kb,   // [bh][784][64]
    const unsigned short* __restrict__ vtb,  // [bh][256][784]
    const float* __restrict__ biases,        // [8*784]
    const int* __restrict__ bias_idxs,       // [784*784]
    unsigned short* __restrict__ U)          // [16*784*2048] bf16 (post-SiLU)
{
  __shared__ unsigned short vt_lds[256 * 72];   // V^T tile: [c][j], stride 72 (144B, 16B-aligned)
  __shared__ unsigned short ps_lds[4 * 16 * 72]; // per-wave P strip: [wave][row][j]
  int tid = threadIdx.x;
  int wave = tid >> 6, lane = tid & 63;
  int quad = lane >> 4, l16 = lane & 15;
  int bh = blockIdx.y;
  int b = bh >> 3, h = bh & 7;
  int qt = blockIdx.x;
  int row_base = qt * 64 + wave * 16;

  // Q A-fragments (2 k-steps over d=64), held in registers for the whole kernel
  short8 qf[2];
  {
    int qrow = row_base + l16;
    if (qrow < Nseq) {
      const unsigned short* qp = qb + ((size_t)bh * Nseq + qrow) * KD;
      qf[0] = *(const short8*)(qp + quad * 8);
      qf[1] = *(const short8*)(qp + 32 + quad * 8);
    } else {
      qf[0] = (short8)0; qf[1] = (short8)0;
    }
  }

  float mrow[4], lrow[4];
  for (int r = 0; r < 4; ++r) { mrow[r] = -1e30f; lrow[r] = 0.0f; }
  floatx4 oacc[16];
  for (int ct = 0; ct < 16; ++ct) oacc[ct] = (floatx4)0.0f;

  for (int kt = 0; kt < 13; ++kt) {
    __syncthreads();   // protect vt_lds from previous iteration's readers
    // stage V^T tile: 256 channels x 64 kv (zero-fill beyond 784; 8 | 784 so chunks align)
    for (int rep = 0; rep < 8; ++rep) {
      int l = rep * 256 + tid;       // 0..2047
      int c = l >> 3;                // 0..255
      int ch = (l & 7) << 3;         // 0..56
      int jg = kt * 64 + ch;
      uint4 val;
      if (jg < Nseq) val = *(const uint4*)&vtb[((size_t)bh * VD + c) * Nseq + jg];
      else           val = make_uint4(0u, 0u, 0u, 0u);
      *(uint4*)&vt_lds[c * 72 + ch] = val;
    }
    __syncthreads();

    // S = (q*scale) K^T : 4 col-tiles x 2 k-steps (K B-frags straight from global)
    floatx4 s4[4];
    for (int jt = 0; jt < 4; ++jt) {
      s4[jt] = (floatx4)0.0f;
      int krow = kt * 64 + jt * 16 + l16;
      short8 kf0, kf1;
      if (krow < Nseq) {
        const unsigned short* kp = kb + ((size_t)bh * Nseq + krow) * KD;
        kf0 = *(const short8*)(kp + quad * 8);
        kf1 = *(const short8*)(kp + 32 + quad * 8);
      } else {
        kf0 = (short8)0; kf1 = (short8)0;
      }
      s4[jt] = __builtin_amdgcn_mfma_f32_16x16x32_bf16(qf[0], kf0, s4[jt], 0, 0, 0);
      s4[jt] = __builtin_amdgcn_mfma_f32_16x16x32_bf16(qf[1], kf1, s4[jt], 0, 0, 0);
    }

    // bias + mask + online softmax (rows quad*4+r, 16-lane groups share a row set)
    for (int r = 0; r < 4; ++r) {
      int ig = row_base + quad * 4 + r;
      int igc = ig < Nseq ? ig : (Nseq - 1);
      float mx = -1e30f;
      for (int jt = 0; jt < 4; ++jt) {
        int jg = kt * 64 + jt * 16 + l16;
        float s = s4[jt][r];
        if (jg < Nseq) s += biases[h * Nseq + bias_idxs[igc * Nseq + jg]];
        else           s = -1e30f;
        s4[jt][r] = s;
        mx = fmaxf(mx, s);
      }
      for (int off = 1; off < 16; off <<= 1) mx = fmaxf(mx, __shfl_xor(mx, off));
      float mN = fmaxf(mrow[r], mx);
      float alpha = exp2f((mrow[r] - mN) * 1.44269504f);
      mrow[r] = mN;
      float ps = 0.0f;
      for (int jt = 0; jt < 4; ++jt) {
        float p = exp2f((s4[jt][r] - mN) * 1.44269504f);
        s4[jt][r] = p;
        ps += p;
      }
      for (int off = 1; off < 16; off <<= 1) ps += __shfl_xor(ps, off);
      lrow[r] = lrow[r] * alpha + ps;
      for (int ct = 0; ct < 16; ++ct) oacc[ct][r] *= alpha;
    }

    // P -> LDS (C-layout -> A-layout round trip; per-wave region, no barrier needed)
    for (int jt = 0; jt < 4; ++jt)
      for (int r = 0; r < 4; ++r)
        ps_lds[wave * 1152 + (quad * 4 + r) * 72 + jt * 16 + l16] = f2bf(s4[jt][r]);

    // O += P V : 16 col-tiles of VD x 2 k-steps over j
    for (int ks = 0; ks < 2; ++ks) {
      short8 pf = *(const short8*)&ps_lds[wave * 1152 + l16 * 72 + ks * 32 + quad * 8];
      for (int ct = 0; ct < 16; ++ct) {
        short8 vf = *(const short8*)&vt_lds[(ct * 16 + l16) * 72 + ks * 32 + quad * 8];
        oacc[ct] = __builtin_amdgcn_mfma_f32_16x16x32_bf16(pf, vf, oacc[ct], 0, 0, 0);
      }
    }
  }

  // epilogue: normalize, SiLU, write U (bf16)
  float inv[4];
  for (int r = 0; r < 4; ++r) inv[r] = 1.0f / lrow[r];
  for (int r = 0; r < 4; ++r) {
    int ig = row_base + quad * 4 + r;
    if (ig >= Nseq) continue;
    size_t base = ((size_t)b * Nseq + ig) * HV + h * VD;
    for (int ct = 0; ct < 16; ++ct) {
      float u = oacc[ct][r] * inv[r];
      float sg = 1.0f / (1.0f + exp2f(-u * 1.44269504f));
      U[base + ct * 16 + l16] = f2bf(u * sg);
    }
  }
}

// ---------------- K3: proj GEMM + BN -> fp32 out ----------------
// A = U [12544][2048] bf16, Bw = wp [512][2048] bf16
__global__ __launch_bounds__(256, 2) void proj_gemm_kernel(
    const unsigned short* __restrict__ A,
    const unsigned short* __restrict__ Bw,
    const float* __restrict__ gamma, const float* __restrict__ beta,
    const float* __restrict__ mean,  const float* __restrict__ var,
    float* __restrict__ out)
{
  const int K = HV;
  __shared__ unsigned short As[128 * LSTR];
  __shared__ unsigned short Bs[128 * LSTR];
  int tid = threadIdx.x;
  int wave = tid >> 6, lane = tid & 63;
  int quad = lane >> 4, l16 = lane & 15;
  int wm = wave >> 1, wn = wave & 1;
  int m0 = blockIdx.y * 128, n0 = blockIdx.x * 128;

  floatx4 acc[4][4];
  for (int i = 0; i < 4; ++i)
    for (int j = 0; j < 4; ++j) acc[i][j] = (floatx4)0.0f;

  for (int k0 = 0; k0 < K; k0 += 32) {
    __syncthreads();
    for (int r = 0; r < 2; ++r) {
      int idx = r * 256 + tid;
      int row = idx >> 2;
      int c8 = (idx & 3) << 3;
      *(uint4*)&As[row * LSTR + c8] = *(const uint4*)&A[(size_t)(m0 + row) * K + k0 + c8];
      *(uint4*)&Bs[row * LSTR + c8] = *(const uint4*)&Bw[(size_t)(n0 + row) * K + k0 + c8];
    }
    __syncthreads();
    short8 af[4], bf[4];
    for (int mt = 0; mt < 4; ++mt)
      af[mt] = *(const short8*)&As[(wm * 64 + mt * 16 + l16) * LSTR + quad * 8];
    for (int nt = 0; nt < 4; ++nt)
      bf[nt] = *(const short8*)&Bs[(wn * 64 + nt * 16 + l16) * LSTR + quad * 8];
    for (int mt = 0; mt < 4; ++mt)
      for (int nt = 0; nt < 4; ++nt)
        acc[mt][nt] = __builtin_amdgcn_mfma_f32_16x16x32_bf16(af[mt], bf[nt], acc[mt][nt], 0, 0, 0);
  }

  for (int nt = 0; nt < 4; ++nt) {
    int o = n0 + wn * 64 + nt * 16 + l16;
    float sc = gamma[o] * rsqrtf(var[o] + 1e-5f);
    float bb = beta[o] - mean[o] * sc;
    for (int mt = 0; mt < 4; ++mt) {
      for (int r = 0; r < 4; ++r) {
        int m = m0 + wm * 64 + mt * 16 + quad * 4 + r;
        out[(size_t)m * DIM + o] = acc[mt][nt][r] * sc + bb;
      }
    }
  }
}

// ---------------- launch ----------------
extern "C" void kernel_launch(void* const* d_in, const int* in_sizes, int n_in,
                              void* d_out, int out_size, void* d_ws, size_t ws_size,
                              hipStream_t stream) {
  const float* x          = (const float*)d_in[0];
  const float* qkv_w      = (const float*)d_in[1];
  const float* qkv_gamma  = (const float*)d_in[2];
  const float* qkv_beta   = (const float*)d_in[3];
  const float* qkv_mean   = (const float*)d_in[4];
  const float* qkv_var    = (const float*)d_in[5];
  const float* att_biases = (const float*)d_in[6];
  const float* proj_w     = (const float*)d_in[7];
  const float* proj_gamma = (const float*)d_in[8];
  const float* proj_beta  = (const float*)d_in[9];
  const float* proj_mean  = (const float*)d_in[10];
  const float* proj_var   = (const float*)d_in[11];
  const int*   bias_idxs  = (const int*)d_in[12];
  float* out = (float*)d_out;

  // workspace layout (bytes; all 16B aligned)
  char* ws = (char*)d_ws;
  unsigned short* xb  = (unsigned short*)(ws);                 // 12544*512
  unsigned short* wq  = (unsigned short*)(ws + 12845056);      // 3072*512
  unsigned short* wp  = (unsigned short*)(ws + 15990784);      // 512*2048
  unsigned short* qo  = (unsigned short*)(ws + 18087936);      // 16*8*784*64
  unsigned short* ko  = (unsigned short*)(ws + 30932992);      // 16*8*784*64
  unsigned short* vto = (unsigned short*)(ws + 43778048);      // 16*8*256*784
  unsigned short* Ub  = (unsigned short*)(ws + 95158272);      // 12544*2048
  // total: 146538496 bytes

  {
    int n4 = (Bsz * Nseq * DIM) / 4;
    cvt4_kernel<<<(n4 + 255) / 256, 256, 0, stream>>>(x, xb, n4);
  }
  {
    int n4 = (QKV_OUT * DIM) / 4;
    cvt4_kernel<<<(n4 + 255) / 256, 256, 0, stream>>>(qkv_w, wq, n4);
  }
  {
    int n4 = (DIM * HV) / 4;
    cvt4_kernel<<<(n4 + 255) / 256, 256, 0, stream>>>(proj_w, wp, n4);
  }

  qkv_gemm_kernel<<<dim3(QKV_OUT / 128, (Bsz * Nseq) / 128), 256, 0, stream>>>(
      xb, wq, qkv_gamma, qkv_beta, qkv_mean, qkv_var, qo, ko, vto);

  attn_kernel<<<dim3(13, Bsz * NH), 256, 0, stream>>>(
      qo, ko, vto, att_biases, bias_idxs, Ub);

  proj_gemm_kernel<<<dim3(DIM / 128, (Bsz * Nseq) / 128), 256, 0, stream>>>(
      Ub, wp, proj_gamma, proj_beta, proj_mean, proj_var, out);
}

// Round 2
// 926.713 us; speedup vs baseline: 1.1738x; 1.1738x over previous
//
#include <hip/hip_runtime.h>

// Problem constants
#define Bsz 16
#define Nseq 784
#define DIM 512
#define NH 8
#define KD 64
#define VD 256
#define QKV_OUT 3072   // (2*64+256)*8
#define HV 2048        // NH*VD
#define NN 614656      // 784*784

typedef __attribute__((ext_vector_type(8))) short short8;
typedef __attribute__((ext_vector_type(4))) float floatx4;

#define LSTR 56   // LDS row stride (bf16 elems): 112B -> 16B aligned, 2-way bank alias only (free)

__device__ __forceinline__ unsigned short f2bf(float f) {
  union { float f; unsigned u; } v; v.f = f;
  unsigned r = v.u + 0x7fffu + ((v.u >> 16) & 1u);
  return (unsigned short)(r >> 16);
}
__device__ __forceinline__ float bf2f(unsigned short u) {
  union { unsigned u; float f; } v; v.u = ((unsigned)u) << 16;
  return v.f;
}

// ---------------- K0: fp32 -> bf16 convert ----------------
__global__ void cvt4_kernel(const float* __restrict__ src,
                            unsigned short* __restrict__ dst, int n4) {
  int i = blockIdx.x * blockDim.x + threadIdx.x;
  int stride = gridDim.x * blockDim.x;
  for (; i < n4; i += stride) {
    float4 v = ((const float4*)src)[i];
    ushort4 o;
    o.x = f2bf(v.x); o.y = f2bf(v.y); o.z = f2bf(v.z); o.w = f2bf(v.w);
    ((ushort4*)dst)[i] = o;
  }
}

// ---------------- K0b: materialize bias table [8][784][784] bf16 ----------------
__global__ void bias_pre_kernel(const float* __restrict__ biases,
                                const int* __restrict__ bias_idxs,
                                unsigned short* __restrict__ bias_tab) {
  int t = blockIdx.x * 256 + threadIdx.x;
  if (t >= NN) return;
  int idx = bias_idxs[t];
  for (int h = 0; h < NH; ++h)
    bias_tab[(size_t)h * NN + t] = f2bf(biases[h * Nseq + idx]);
}

// ---------------- K1: QKV GEMM + BN + scatter q/k/vt ----------------
__global__ __launch_bounds__(256, 2) void qkv_gemm_kernel(
    const unsigned short* __restrict__ A,
    const unsigned short* __restrict__ Bw,
    const float* __restrict__ gamma, const float* __restrict__ beta,
    const float* __restrict__ mean,  const float* __restrict__ var,
    unsigned short* __restrict__ qo,   // [B,H,N,64] (pre-scaled by 0.125)
    unsigned short* __restrict__ ko,   // [B,H,N,64]
    unsigned short* __restrict__ vto)  // [B,H,256,N]
{
  const int K = DIM;
  __shared__ unsigned short As[128 * LSTR];
  __shared__ unsigned short Bs[128 * LSTR];
  int tid = threadIdx.x;
  int wave = tid >> 6, lane = tid & 63;
  int quad = lane >> 4, l16 = lane & 15;
  int wm = wave >> 1, wn = wave & 1;
  int m0 = blockIdx.y * 128, n0 = blockIdx.x * 128;

  floatx4 acc[4][4];
  for (int i = 0; i < 4; ++i)
    for (int j = 0; j < 4; ++j) acc[i][j] = (floatx4)0.0f;

  for (int k0 = 0; k0 < K; k0 += 32) {
    __syncthreads();
    for (int r = 0; r < 2; ++r) {
      int idx = r * 256 + tid;
      int row = idx >> 2;
      int c8 = (idx & 3) << 3;
      *(uint4*)&As[row * LSTR + c8] = *(const uint4*)&A[(size_t)(m0 + row) * K + k0 + c8];
      *(uint4*)&Bs[row * LSTR + c8] = *(const uint4*)&Bw[(size_t)(n0 + row) * K + k0 + c8];
    }
    __syncthreads();
    short8 af[4], bfr[4];
    for (int mt = 0; mt < 4; ++mt)
      af[mt] = *(const short8*)&As[(wm * 64 + mt * 16 + l16) * LSTR + quad * 8];
    for (int nt = 0; nt < 4; ++nt)
      bfr[nt] = *(const short8*)&Bs[(wn * 64 + nt * 16 + l16) * LSTR + quad * 8];
    for (int mt = 0; mt < 4; ++mt)
      for (int nt = 0; nt < 4; ++nt)
        acc[mt][nt] = __builtin_amdgcn_mfma_f32_16x16x32_bf16(af[mt], bfr[nt], acc[mt][nt], 0, 0, 0);
  }

  for (int nt = 0; nt < 4; ++nt) {
    int o = n0 + wn * 64 + nt * 16 + l16;
    float sc = gamma[o] * rsqrtf(var[o] + 1e-5f);
    float bb = beta[o] - mean[o] * sc;
    int h = o / 384;
    int j = o - h * 384;
    for (int mt = 0; mt < 4; ++mt) {
      for (int r = 0; r < 4; ++r) {
        int m = m0 + wm * 64 + mt * 16 + quad * 4 + r;
        int b = m / 784;
        int n = m - b * 784;
        float y = acc[mt][nt][r] * sc + bb;
        if (j < 64) {
          qo[(((size_t)b * NH + h) * Nseq + n) * KD + j] = f2bf(y * 0.125f);
        } else if (j < 128) {
          ko[(((size_t)b * NH + h) * Nseq + n) * KD + (j - 64)] = f2bf(y);
        } else {
          vto[(((size_t)b * NH + h) * VD + (j - 128)) * Nseq + n] = f2bf(y);
        }
      }
    }
  }
}

// ---------------- K2: flash attention + bias + softmax + SiLU ----------------
// 1-D grid of 13*128 blocks; XCD-aware decode so all 13 q-tiles of one bh
// land on the same XCD (bh%8==h also pins one head's bias slice per XCD L2).
__global__ __launch_bounds__(256, 2) void attn_kernel(
    const unsigned short* __restrict__ qb,   // [bh][784][64] (pre-scaled)
    const unsigned short* __restrict__ kb,   // [bh][784][64]
    const unsigned short* __restrict__ vtb,  // [bh][256][784]
    const unsigned short* __restrict__ bias_tab, // [8][784][784] bf16
    unsigned short* __restrict__ U)          // [16*784*2048] bf16 (post-SiLU)
{
  __shared__ unsigned short vt_lds[256 * 72];
  __shared__ unsigned short ps_lds[4 * 16 * 72];
  int tid = threadIdx.x;
  int wave = tid >> 6, lane = tid & 63;
  int quad = lane >> 4, l16 = lane & 15;

  int L = blockIdx.x;
  int xcd = L & 7;
  int seq = L >> 3;
  int qt = seq % 13;
  int bh = (seq / 13) * 8 + xcd;   // bh % 8 == h == xcd
  int b = bh >> 3, h = bh & 7;
  int row_base = qt * 64 + wave * 16;

  const unsigned short* brow = bias_tab + (size_t)h * NN;

  short8 qf[2];
  {
    int qrow = row_base + l16;
    if (qrow < Nseq) {
      const unsigned short* qp = qb + ((size_t)bh * Nseq + qrow) * KD;
      qf[0] = *(const short8*)(qp + quad * 8);
      qf[1] = *(const short8*)(qp + 32 + quad * 8);
    } else {
      qf[0] = (short8)0; qf[1] = (short8)0;
    }
  }

  float mrow[4], lrow[4];
  for (int r = 0; r < 4; ++r) { mrow[r] = -1e30f; lrow[r] = 0.0f; }
  floatx4 oacc[16];
  for (int ct = 0; ct < 16; ++ct) oacc[ct] = (floatx4)0.0f;

  for (int kt = 0; kt < 13; ++kt) {
    __syncthreads();
    // stage V^T tile: 256 channels x 64 kv
    for (int rep = 0; rep < 8; ++rep) {
      int l = rep * 256 + tid;
      int c = l >> 3;
      int ch = (l & 7) << 3;
      int jg = kt * 64 + ch;
      uint4 val;
      if (jg < Nseq) val = *(const uint4*)&vtb[((size_t)bh * VD + c) * Nseq + jg];
      else           val = make_uint4(0u, 0u, 0u, 0u);
      *(uint4*)&vt_lds[c * 72 + ch] = val;
    }
    __syncthreads();

    // S = (q*scale) K^T
    floatx4 s4[4];
    for (int jt = 0; jt < 4; ++jt) {
      s4[jt] = (floatx4)0.0f;
      int krow = kt * 64 + jt * 16 + l16;
      short8 kf0, kf1;
      if (krow < Nseq) {
        const unsigned short* kp = kb + ((size_t)bh * Nseq + krow) * KD;
        kf0 = *(const short8*)(kp + quad * 8);
        kf1 = *(const short8*)(kp + 32 + quad * 8);
      } else {
        kf0 = (short8)0; kf1 = (short8)0;
      }
      s4[jt] = __builtin_amdgcn_mfma_f32_16x16x32_bf16(qf[0], kf0, s4[jt], 0, 0, 0);
      s4[jt] = __builtin_amdgcn_mfma_f32_16x16x32_bf16(qf[1], kf1, s4[jt], 0, 0, 0);
    }

    // bias (coalesced bf16 table) + mask + online softmax
    for (int r = 0; r < 4; ++r) {
      int ig = row_base + quad * 4 + r;
      int igc = ig < Nseq ? ig : (Nseq - 1);
      const unsigned short* bp = brow + (size_t)igc * Nseq + kt * 64 + l16;
      float mx = -1e30f;
      for (int jt = 0; jt < 4; ++jt) {
        int jg = kt * 64 + jt * 16 + l16;
        float s = s4[jt][r];
        if (jg < Nseq) s += bf2f(bp[jt * 16]);
        else           s = -1e30f;
        s4[jt][r] = s;
        mx = fmaxf(mx, s);
      }
      for (int off = 1; off < 16; off <<= 1) mx = fmaxf(mx, __shfl_xor(mx, off));
      float mN = fmaxf(mrow[r], mx);
      float alpha = exp2f((mrow[r] - mN) * 1.44269504f);
      mrow[r] = mN;
      float ps = 0.0f;
      for (int jt = 0; jt < 4; ++jt) {
        float p = exp2f((s4[jt][r] - mN) * 1.44269504f);
        s4[jt][r] = p;
        ps += p;
      }
      lrow[r] = lrow[r] * alpha + ps;   // per-lane partial; reduced in epilogue
      for (int ct = 0; ct < 16; ++ct) oacc[ct][r] *= alpha;
    }

    // P -> LDS (C-layout -> A-layout; per-wave region)
    for (int jt = 0; jt < 4; ++jt)
      for (int r = 0; r < 4; ++r)
        ps_lds[wave * 1152 + (quad * 4 + r) * 72 + jt * 16 + l16] = f2bf(s4[jt][r]);

    // O += P V
    for (int ks = 0; ks < 2; ++ks) {
      short8 pf = *(const short8*)&ps_lds[wave * 1152 + l16 * 72 + ks * 32 + quad * 8];
      for (int ct = 0; ct < 16; ++ct) {
        short8 vf = *(const short8*)&vt_lds[(ct * 16 + l16) * 72 + ks * 32 + quad * 8];
        oacc[ct] = __builtin_amdgcn_mfma_f32_16x16x32_bf16(pf, vf, oacc[ct], 0, 0, 0);
      }
    }
  }

  // epilogue: reduce l across the 16-lane group, normalize, SiLU, write U
  float inv[4];
  for (int r = 0; r < 4; ++r) {
    float tot = lrow[r];
    for (int off = 1; off < 16; off <<= 1) tot += __shfl_xor(tot, off);
    inv[r] = 1.0f / tot;
  }
  for (int r = 0; r < 4; ++r) {
    int ig = row_base + quad * 4 + r;
    if (ig >= Nseq) continue;
    size_t base = ((size_t)b * Nseq + ig) * HV + h * VD;
    for (int ct = 0; ct < 16; ++ct) {
      float u = oacc[ct][r] * inv[r];
      float sg = 1.0f / (1.0f + exp2f(-u * 1.44269504f));
      U[base + ct * 16 + l16] = f2bf(u * sg);
    }
  }
}

// ---------------- K3: proj GEMM + BN -> fp32 out ----------------
__global__ __launch_bounds__(256, 2) void proj_gemm_kernel(
    const unsigned short* __restrict__ A,
    const unsigned short* __restrict__ Bw,
    const float* __restrict__ gamma, const float* __restrict__ beta,
    const float* __restrict__ mean,  const float* __restrict__ var,
    float* __restrict__ out)
{
  const int K = HV;
  __shared__ unsigned short As[128 * LSTR];
  __shared__ unsigned short Bs[128 * LSTR];
  int tid = threadIdx.x;
  int wave = tid >> 6, lane = tid & 63;
  int quad = lane >> 4, l16 = lane & 15;
  int wm = wave >> 1, wn = wave & 1;
  int m0 = blockIdx.y * 128, n0 = blockIdx.x * 128;

  floatx4 acc[4][4];
  for (int i = 0; i < 4; ++i)
    for (int j = 0; j < 4; ++j) acc[i][j] = (floatx4)0.0f;

  for (int k0 = 0; k0 < K; k0 += 32) {
    __syncthreads();
    for (int r = 0; r < 2; ++r) {
      int idx = r * 256 + tid;
      int row = idx >> 2;
      int c8 = (idx & 3) << 3;
      *(uint4*)&As[row * LSTR + c8] = *(const uint4*)&A[(size_t)(m0 + row) * K + k0 + c8];
      *(uint4*)&Bs[row * LSTR + c8] = *(const uint4*)&Bw[(size_t)(n0 + row) * K + k0 + c8];
    }
    __syncthreads();
    short8 af[4], bfr[4];
    for (int mt = 0; mt < 4; ++mt)
      af[mt] = *(const short8*)&As[(wm * 64 + mt * 16 + l16) * LSTR + quad * 8];
    for (int nt = 0; nt < 4; ++nt)
      bfr[nt] = *(const short8*)&Bs[(wn * 64 + nt * 16 + l16) * LSTR + quad * 8];
    for (int mt = 0; mt < 4; ++mt)
      for (int nt = 0; nt < 4; ++nt)
        acc[mt][nt] = __builtin_amdgcn_mfma_f32_16x16x32_bf16(af[mt], bfr[nt], acc[mt][nt], 0, 0, 0);
  }

  for (int nt = 0; nt < 4; ++nt) {
    int o = n0 + wn * 64 + nt * 16 + l16;
    float sc = gamma[o] * rsqrtf(var[o] + 1e-5f);
    float bb = beta[o] - mean[o] * sc;
    for (int mt = 0; mt < 4; ++mt) {
      for (int r = 0; r < 4; ++r) {
        int m = m0 + wm * 64 + mt * 16 + quad * 4 + r;
        out[(size_t)m * DIM + o] = acc[mt][nt][r] * sc + bb;
      }
    }
  }
}

// ---------------- launch ----------------
extern "C" void kernel_launch(void* const* d_in, const int* in_sizes, int n_in,
                              void* d_out, int out_size, void* d_ws, size_t ws_size,
                              hipStream_t stream) {
  const float* x          = (const float*)d_in[0];
  const float* qkv_w      = (const float*)d_in[1];
  const float* qkv_gamma  = (const float*)d_in[2];
  const float* qkv_beta   = (const float*)d_in[3];
  const float* qkv_mean   = (const float*)d_in[4];
  const float* qkv_var    = (const float*)d_in[5];
  const float* att_biases = (const float*)d_in[6];
  const float* proj_w     = (const float*)d_in[7];
  const float* proj_gamma = (const float*)d_in[8];
  const float* proj_beta  = (const float*)d_in[9];
  const float* proj_mean  = (const float*)d_in[10];
  const float* proj_var   = (const float*)d_in[11];
  const int*   bias_idxs  = (const int*)d_in[12];
  float* out = (float*)d_out;

  // workspace layout (bytes; all 16B aligned). bias_tab ALIASES xb: xb is
  // dead after qkv_gemm, bias_pre runs after it on the same stream.
  char* ws = (char*)d_ws;
  unsigned short* xb  = (unsigned short*)(ws);                 // 12544*512 (12.85 MB)
  unsigned short* bias_tab = (unsigned short*)(ws);            // 8*784*784 bf16 (9.83 MB) — aliases xb
  unsigned short* wq  = (unsigned short*)(ws + 12845056);      // 3072*512
  unsigned short* wp  = (unsigned short*)(ws + 15990784);      // 512*2048
  unsigned short* qo  = (unsigned short*)(ws + 18087936);      // 16*8*784*64
  unsigned short* ko  = (unsigned short*)(ws + 30932992);      // 16*8*784*64
  unsigned short* vto = (unsigned short*)(ws + 43778048);      // 16*8*256*784
  unsigned short* Ub  = (unsigned short*)(ws + 95158272);      // 12544*2048
  // total: 146538496 bytes

  {
    int n4 = (Bsz * Nseq * DIM) / 4;
    cvt4_kernel<<<(n4 + 255) / 256, 256, 0, stream>>>(x, xb, n4);
  }
  {
    int n4 = (QKV_OUT * DIM) / 4;
    cvt4_kernel<<<(n4 + 255) / 256, 256, 0, stream>>>(qkv_w, wq, n4);
  }
  {
    int n4 = (DIM * HV) / 4;
    cvt4_kernel<<<(n4 + 255) / 256, 256, 0, stream>>>(proj_w, wp, n4);
  }

  qkv_gemm_kernel<<<dim3(QKV_OUT / 128, (Bsz * Nseq) / 128), 256, 0, stream>>>(
      xb, wq, qkv_gamma, qkv_beta, qkv_mean, qkv_var, qo, ko, vto);

  bias_pre_kernel<<<(NN + 255) / 256, 256, 0, stream>>>(att_biases, bias_idxs, bias_tab);

  attn_kernel<<<13 * Bsz * NH, 256, 0, stream>>>(qo, ko, vto, bias_tab, Ub);

  proj_gemm_kernel<<<dim3(DIM / 128, (Bsz * Nseq) / 128), 256, 0, stream>>>(
      Ub, wp, proj_gamma, proj_beta, proj_mean, proj_var, out);
}

// Round 3
// 543.183 us; speedup vs baseline: 2.0027x; 1.7061x over previous
//
#include <hip/hip_runtime.h>

// Problem constants
#define Bsz 16
#define Nseq 784
#define DIM 512
#define NH 8
#define KD 64
#define VD 256
#define QKV_OUT 3072   // (2*64+256)*8
#define HV 2048        // NH*VD
#define NN 614656      // 784*784

typedef __attribute__((ext_vector_type(8))) short short8;
typedef __attribute__((ext_vector_type(4))) float floatx4;

#define LSTR 56   // LDS row stride for GEMM staging (bf16): 112B, 16B-aligned
#define OSTR 136  // LDS row stride for epilogue tile (bf16): 272B, 16B-aligned

__device__ __forceinline__ unsigned short f2bf(float f) {
  union { float f; unsigned u; } v; v.f = f;
  unsigned r = v.u + 0x7fffu + ((v.u >> 16) & 1u);
  return (unsigned short)(r >> 16);
}
__device__ __forceinline__ float bf2f(unsigned short u) {
  union { unsigned u; float f; } v; v.u = ((unsigned)u) << 16;
  return v.f;
}

// ---------------- K0: fp32 -> bf16 convert ----------------
__global__ void cvt4_kernel(const float* __restrict__ src,
                            unsigned short* __restrict__ dst, int n4) {
  int i = blockIdx.x * blockDim.x + threadIdx.x;
  int stride = gridDim.x * blockDim.x;
  for (; i < n4; i += stride) {
    float4 v = ((const float4*)src)[i];
    ushort4 o;
    o.x = f2bf(v.x); o.y = f2bf(v.y); o.z = f2bf(v.z); o.w = f2bf(v.w);
    ((ushort4*)dst)[i] = o;
  }
}

// ---------------- K0b: materialize bias table [8][784][784] bf16 ----------------
__global__ void bias_pre_kernel(const float* __restrict__ biases,
                                const int* __restrict__ bias_idxs,
                                unsigned short* __restrict__ bias_tab) {
  int t = blockIdx.x * 256 + threadIdx.x;
  if (t >= NN) return;
  int idx = bias_idxs[t];
  for (int h = 0; h < NH; ++h)
    bias_tab[(size_t)h * NN + t] = f2bf(biases[h * Nseq + idx]);
}

// ---------------- K1: QKV GEMM + BN + LDS-staged coalesced scatter ----------------
// A = xb [12544][512], Bw = wq [3072][512]. Each 128-channel tile is either a
// QK tile (n0%384==0) or a V tile — epilogue stages bf16 tile in LDS, then
// writes 16B line-complete chunks.
__global__ __launch_bounds__(256, 2) void qkv_gemm_kernel(
    const unsigned short* __restrict__ A,
    const unsigned short* __restrict__ Bw,
    const float* __restrict__ gamma, const float* __restrict__ beta,
    const float* __restrict__ mean,  const float* __restrict__ var,
    unsigned short* __restrict__ qo,   // [B,H,N,64] (pre-scaled by 0.125)
    unsigned short* __restrict__ ko,   // [B,H,N,64]
    unsigned short* __restrict__ vto)  // [B,H,256,N]
{
  const int K = DIM;
  __shared__ unsigned short smem[128 * OSTR];   // 34,816 B; aliases As/Bs
  unsigned short* As = smem;                    // 128*LSTR
  unsigned short* Bs = smem + 128 * LSTR;       // 128*LSTR
  int tid = threadIdx.x;
  int wave = tid >> 6, lane = tid & 63;
  int quad = lane >> 4, l16 = lane & 15;
  int wm = wave >> 1, wn = wave & 1;
  int m0 = blockIdx.y * 128, n0 = blockIdx.x * 128;

  floatx4 acc[4][4];
  for (int i = 0; i < 4; ++i)
    for (int j = 0; j < 4; ++j) acc[i][j] = (floatx4)0.0f;

  for (int k0 = 0; k0 < K; k0 += 32) {
    __syncthreads();
    for (int r = 0; r < 2; ++r) {
      int idx = r * 256 + tid;
      int row = idx >> 2;
      int c8 = (idx & 3) << 3;
      *(uint4*)&As[row * LSTR + c8] = *(const uint4*)&A[(size_t)(m0 + row) * K + k0 + c8];
      *(uint4*)&Bs[row * LSTR + c8] = *(const uint4*)&Bw[(size_t)(n0 + row) * K + k0 + c8];
    }
    __syncthreads();
    short8 af[4], bfr[4];
    for (int mt = 0; mt < 4; ++mt)
      af[mt] = *(const short8*)&As[(wm * 64 + mt * 16 + l16) * LSTR + quad * 8];
    for (int nt = 0; nt < 4; ++nt)
      bfr[nt] = *(const short8*)&Bs[(wn * 64 + nt * 16 + l16) * LSTR + quad * 8];
    for (int mt = 0; mt < 4; ++mt)
      for (int nt = 0; nt < 4; ++nt)
        acc[mt][nt] = __builtin_amdgcn_mfma_f32_16x16x32_bf16(af[mt], bfr[nt], acc[mt][nt], 0, 0, 0);
  }

  int tt = n0 % 384;        // 0 => QK tile; 128/256 => V tile
  int h = n0 / 384;
  __syncthreads();          // frag reads done before smem reuse

  if (tt == 0) {
    // stage [m_local][j_local], j_local = wn*64+nt*16+l16 (q: j<64, k: j>=64)
    for (int nt = 0; nt < 4; ++nt) {
      int o = n0 + wn * 64 + nt * 16 + l16;
      float sc = gamma[o] * rsqrtf(var[o] + 1e-5f);
      float bb = beta[o] - mean[o] * sc;
      if (wn == 0) { sc *= 0.125f; bb *= 0.125f; }   // q pre-scale
      int jl = wn * 64 + nt * 16 + l16;
      for (int mt = 0; mt < 4; ++mt)
        for (int r = 0; r < 4; ++r) {
          int ml = wm * 64 + mt * 16 + quad * 4 + r;
          smem[ml * OSTR + jl] = f2bf(acc[mt][nt][r] * sc + bb);
        }
    }
    __syncthreads();
    for (int i = 0; i < 8; ++i) {
      int c = i * 256 + tid;           // 0..2047
      int ml = c >> 4, jc = c & 15;    // row, 16B chunk
      int m = m0 + ml;
      int b = m / 784, n = m - b * 784;
      uint4 v = *(uint4*)&smem[ml * OSTR + jc * 8];
      int j = jc * 8;
      if (j < 64) *(uint4*)&qo[(((size_t)b * NH + h) * Nseq + n) * KD + j] = v;
      else        *(uint4*)&ko[(((size_t)b * NH + h) * Nseq + n) * KD + (j - 64)] = v;
    }
  } else {
    // stage [c_local][m_local]
    for (int nt = 0; nt < 4; ++nt) {
      int o = n0 + wn * 64 + nt * 16 + l16;
      float sc = gamma[o] * rsqrtf(var[o] + 1e-5f);
      float bb = beta[o] - mean[o] * sc;
      int cl = wn * 64 + nt * 16 + l16;
      for (int mt = 0; mt < 4; ++mt)
        for (int r = 0; r < 4; ++r) {
          int ml = wm * 64 + mt * 16 + quad * 4 + r;
          smem[cl * OSTR + ml] = f2bf(acc[mt][nt][r] * sc + bb);
        }
    }
    __syncthreads();
    int cbase = tt - 128;              // 0 or 128
    for (int i = 0; i < 8; ++i) {
      int c = i * 256 + tid;
      int cl = c >> 4, mc = c & 15;
      int m = m0 + mc * 8;             // 8|784 => chunk never straddles b
      int b = m / 784, n = m - b * 784;
      uint4 v = *(uint4*)&smem[cl * OSTR + mc * 8];
      *(uint4*)&vto[(((size_t)b * NH + h) * VD + cbase + cl) * Nseq + n] = v;
    }
  }
}

// ---------------- K2: flash attention + bias + softmax + SiLU ----------------
__global__ __launch_bounds__(256, 2) void attn_kernel(
    const unsigned short* __restrict__ qb,   // [bh][784][64] (pre-scaled)
    const unsigned short* __restrict__ kb,   // [bh][784][64]
    const unsigned short* __restrict__ vtb,  // [bh][256][784]
    const unsigned short* __restrict__ bias_tab, // [8][784][784] bf16
    unsigned short* __restrict__ U)          // [16*784*2048] bf16 (post-SiLU)
{
  __shared__ unsigned short vt_lds[256 * 72];
  __shared__ unsigned short ps_lds[4 * 16 * 72];
  int tid = threadIdx.x;
  int wave = tid >> 6, lane = tid & 63;
  int quad = lane >> 4, l16 = lane & 15;

  int L = blockIdx.x;
  int xcd = L & 7;
  int seq = L >> 3;
  int qt = seq % 13;
  int bh = (seq / 13) * 8 + xcd;   // bh % 8 == h == xcd
  int b = bh >> 3, h = bh & 7;
  int row_base = qt * 64 + wave * 16;

  const unsigned short* brow = bias_tab + (size_t)h * NN;

  short8 qf[2];
  {
    int qrow = row_base + l16;
    if (qrow < Nseq) {
      const unsigned short* qp = qb + ((size_t)bh * Nseq + qrow) * KD;
      qf[0] = *(const short8*)(qp + quad * 8);
      qf[1] = *(const short8*)(qp + 32 + quad * 8);
    } else {
      qf[0] = (short8)0; qf[1] = (short8)0;
    }
  }

  float mrow[4], lrow[4];
  for (int r = 0; r < 4; ++r) { mrow[r] = -1e30f; lrow[r] = 0.0f; }
  floatx4 oacc[16];
  for (int ct = 0; ct < 16; ++ct) oacc[ct] = (floatx4)0.0f;

  for (int kt = 0; kt < 13; ++kt) {
    __syncthreads();
    for (int rep = 0; rep < 8; ++rep) {
      int l = rep * 256 + tid;
      int c = l >> 3;
      int ch = (l & 7) << 3;
      int jg = kt * 64 + ch;
      uint4 val;
      if (jg < Nseq) val = *(const uint4*)&vtb[((size_t)bh * VD + c) * Nseq + jg];
      else           val = make_uint4(0u, 0u, 0u, 0u);
      *(uint4*)&vt_lds[c * 72 + ch] = val;
    }
    __syncthreads();

    floatx4 s4[4];
    for (int jt = 0; jt < 4; ++jt) {
      s4[jt] = (floatx4)0.0f;
      int krow = kt * 64 + jt * 16 + l16;
      short8 kf0, kf1;
      if (krow < Nseq) {
        const unsigned short* kp = kb + ((size_t)bh * Nseq + krow) * KD;
        kf0 = *(const short8*)(kp + quad * 8);
        kf1 = *(const short8*)(kp + 32 + quad * 8);
      } else {
        kf0 = (short8)0; kf1 = (short8)0;
      }
      s4[jt] = __builtin_amdgcn_mfma_f32_16x16x32_bf16(qf[0], kf0, s4[jt], 0, 0, 0);
      s4[jt] = __builtin_amdgcn_mfma_f32_16x16x32_bf16(qf[1], kf1, s4[jt], 0, 0, 0);
    }

    for (int r = 0; r < 4; ++r) {
      int ig = row_base + quad * 4 + r;
      int igc = ig < Nseq ? ig : (Nseq - 1);
      const unsigned short* bp = brow + (size_t)igc * Nseq + kt * 64 + l16;
      float mx = -1e30f;
      for (int jt = 0; jt < 4; ++jt) {
        int jg = kt * 64 + jt * 16 + l16;
        float s = s4[jt][r];
        if (jg < Nseq) s += bf2f(bp[jt * 16]);
        else           s = -1e30f;
        s4[jt][r] = s;
        mx = fmaxf(mx, s);
      }
      for (int off = 1; off < 16; off <<= 1) mx = fmaxf(mx, __shfl_xor(mx, off));
      float mN = fmaxf(mrow[r], mx);
      float alpha = exp2f((mrow[r] - mN) * 1.44269504f);
      mrow[r] = mN;
      float ps = 0.0f;
      for (int jt = 0; jt < 4; ++jt) {
        float p = exp2f((s4[jt][r] - mN) * 1.44269504f);
        s4[jt][r] = p;
        ps += p;
      }
      lrow[r] = lrow[r] * alpha + ps;   // per-lane partial; reduced in epilogue
      for (int ct = 0; ct < 16; ++ct) oacc[ct][r] *= alpha;
    }

    for (int jt = 0; jt < 4; ++jt)
      for (int r = 0; r < 4; ++r)
        ps_lds[wave * 1152 + (quad * 4 + r) * 72 + jt * 16 + l16] = f2bf(s4[jt][r]);

    for (int ks = 0; ks < 2; ++ks) {
      short8 pf = *(const short8*)&ps_lds[wave * 1152 + l16 * 72 + ks * 32 + quad * 8];
      for (int ct = 0; ct < 16; ++ct) {
        short8 vf = *(const short8*)&vt_lds[(ct * 16 + l16) * 72 + ks * 32 + quad * 8];
        oacc[ct] = __builtin_amdgcn_mfma_f32_16x16x32_bf16(pf, vf, oacc[ct], 0, 0, 0);
      }
    }
  }

  float inv[4];
  for (int r = 0; r < 4; ++r) {
    float tot = lrow[r];
    for (int off = 1; off < 16; off <<= 1) tot += __shfl_xor(tot, off);
    inv[r] = 1.0f / tot;
  }
  for (int r = 0; r < 4; ++r) {
    int ig = row_base + quad * 4 + r;
    if (ig >= Nseq) continue;
    size_t base = ((size_t)b * Nseq + ig) * HV + h * VD;
    for (int ct = 0; ct < 16; ++ct) {
      float u = oacc[ct][r] * inv[r];
      float sg = 1.0f / (1.0f + exp2f(-u * 1.44269504f));
      U[base + ct * 16 + l16] = f2bf(u * sg);
    }
  }
}

// ---------------- K3: proj GEMM (operand-swapped) + BN -> fp32 out ----------------
// A-operand = wp rows (o), B-operand = Ub rows (m): D[o][m] => lane holds 4
// consecutive o => float4 stores, 4 quads complete 64B lines exactly.
__global__ __launch_bounds__(256, 2) void proj_gemm_kernel(
    const unsigned short* __restrict__ Ubuf,  // [12544][2048]
    const unsigned short* __restrict__ Wp,    // [512][2048]
    const float* __restrict__ gamma, const float* __restrict__ beta,
    const float* __restrict__ mean,  const float* __restrict__ var,
    float* __restrict__ out)                  // [12544][512]
{
  const int K = HV;
  __shared__ unsigned short As[128 * LSTR];   // wp rows (o)
  __shared__ unsigned short Bs[128 * LSTR];   // Ub rows (m)
  int tid = threadIdx.x;
  int wave = tid >> 6, lane = tid & 63;
  int quad = lane >> 4, l16 = lane & 15;
  int wm = wave >> 1, wn = wave & 1;
  int o0 = blockIdx.y * 128, mB = blockIdx.x * 128;

  floatx4 acc[4][4];
  for (int i = 0; i < 4; ++i)
    for (int j = 0; j < 4; ++j) acc[i][j] = (floatx4)0.0f;

  for (int k0 = 0; k0 < K; k0 += 32) {
    __syncthreads();
    for (int r = 0; r < 2; ++r) {
      int idx = r * 256 + tid;
      int row = idx >> 2;
      int c8 = (idx & 3) << 3;
      *(uint4*)&As[row * LSTR + c8] = *(const uint4*)&Wp[(size_t)(o0 + row) * K + k0 + c8];
      *(uint4*)&Bs[row * LSTR + c8] = *(const uint4*)&Ubuf[(size_t)(mB + row) * K + k0 + c8];
    }
    __syncthreads();
    short8 af[4], bfr[4];
    for (int mt = 0; mt < 4; ++mt)
      af[mt] = *(const short8*)&As[(wm * 64 + mt * 16 + l16) * LSTR + quad * 8];
    for (int nt = 0; nt < 4; ++nt)
      bfr[nt] = *(const short8*)&Bs[(wn * 64 + nt * 16 + l16) * LSTR + quad * 8];
    for (int mt = 0; mt < 4; ++mt)
      for (int nt = 0; nt < 4; ++nt)
        acc[mt][nt] = __builtin_amdgcn_mfma_f32_16x16x32_bf16(af[mt], bfr[nt], acc[mt][nt], 0, 0, 0);
  }

  for (int mt = 0; mt < 4; ++mt) {
    int ob = o0 + wm * 64 + mt * 16 + quad * 4;    // o base, +r for r=0..3
    float4 g = *(const float4*)&gamma[ob];
    float4 vr = *(const float4*)&var[ob];
    float4 mn = *(const float4*)&mean[ob];
    float4 bt = *(const float4*)&beta[ob];
    float sc0 = g.x * rsqrtf(vr.x + 1e-5f), bb0 = bt.x - mn.x * sc0;
    float sc1 = g.y * rsqrtf(vr.y + 1e-5f), bb1 = bt.y - mn.y * sc1;
    float sc2 = g.z * rsqrtf(vr.z + 1e-5f), bb2 = bt.z - mn.z * sc2;
    float sc3 = g.w * rsqrtf(vr.w + 1e-5f), bb3 = bt.w - mn.w * sc3;
    for (int nt = 0; nt < 4; ++nt) {
      int m = mB + wn * 64 + nt * 16 + l16;
      float4 v;
      v.x = acc[mt][nt][0] * sc0 + bb0;
      v.y = acc[mt][nt][1] * sc1 + bb1;
      v.z = acc[mt][nt][2] * sc2 + bb2;
      v.w = acc[mt][nt][3] * sc3 + bb3;
      *(float4*)&out[(size_t)m * DIM + ob] = v;
    }
  }
}

// ---------------- launch ----------------
extern "C" void kernel_launch(void* const* d_in, const int* in_sizes, int n_in,
                              void* d_out, int out_size, void* d_ws, size_t ws_size,
                              hipStream_t stream) {
  const float* x          = (const float*)d_in[0];
  const float* qkv_w      = (const float*)d_in[1];
  const float* qkv_gamma  = (const float*)d_in[2];
  const float* qkv_beta   = (const float*)d_in[3];
  const float* qkv_mean   = (const float*)d_in[4];
  const float* qkv_var    = (const float*)d_in[5];
  const float* att_biases = (const float*)d_in[6];
  const float* proj_w     = (const float*)d_in[7];
  const float* proj_gamma = (const float*)d_in[8];
  const float* proj_beta  = (const float*)d_in[9];
  const float* proj_mean  = (const float*)d_in[10];
  const float* proj_var   = (const float*)d_in[11];
  const int*   bias_idxs  = (const int*)d_in[12];
  float* out = (float*)d_out;

  char* ws = (char*)d_ws;
  unsigned short* xb  = (unsigned short*)(ws);                 // 12544*512 (12.85 MB)
  unsigned short* bias_tab = (unsigned short*)(ws);            // 8*784*784 bf16 — aliases xb (dead after qkv_gemm)
  unsigned short* wq  = (unsigned short*)(ws + 12845056);      // 3072*512
  unsigned short* wp  = (unsigned short*)(ws + 15990784);      // 512*2048
  unsigned short* qo  = (unsigned short*)(ws + 18087936);      // 16*8*784*64
  unsigned short* ko  = (unsigned short*)(ws + 30932992);      // 16*8*784*64
  unsigned short* vto = (unsigned short*)(ws + 43778048);      // 16*8*256*784
  unsigned short* Ub  = (unsigned short*)(ws + 95158272);      // 12544*2048
  // total: 146538496 bytes

  {
    int n4 = (Bsz * Nseq * DIM) / 4;
    cvt4_kernel<<<(n4 + 255) / 256, 256, 0, stream>>>(x, xb, n4);
  }
  {
    int n4 = (QKV_OUT * DIM) / 4;
    cvt4_kernel<<<(n4 + 255) / 256, 256, 0, stream>>>(qkv_w, wq, n4);
  }
  {
    int n4 = (DIM * HV) / 4;
    cvt4_kernel<<<(n4 + 255) / 256, 256, 0, stream>>>(proj_w, wp, n4);
  }

  qkv_gemm_kernel<<<dim3(QKV_OUT / 128, (Bsz * Nseq) / 128), 256, 0, stream>>>(
      xb, wq, qkv_gamma, qkv_beta, qkv_mean, qkv_var, qo, ko, vto);

  bias_pre_kernel<<<(NN + 255) / 256, 256, 0, stream>>>(att_biases, bias_idxs, bias_tab);

  attn_kernel<<<13 * Bsz * NH, 256, 0, stream>>>(qo, ko, vto, bias_tab, Ub);

  proj_gemm_kernel<<<dim3((Bsz * Nseq) / 128, DIM / 128), 256, 0, stream>>>(
      Ub, wp, proj_gamma, proj_beta, proj_mean, proj_var, out);
}

// Round 4
// 500.566 us; speedup vs baseline: 2.1732x; 1.0851x over previous
//
#include <hip/hip_runtime.h>

// Problem constants
#define Bsz 16
#define Nseq 784
#define DIM 512
#define NH 8
#define KD 64
#define VD 256
#define QKV_OUT 3072   // (2*64+256)*8
#define HV 2048        // NH*VD
#define NN 614656      // 784*784

typedef __attribute__((ext_vector_type(8))) short short8;
typedef __attribute__((ext_vector_type(4))) float floatx4;

#define LSTR 56   // LDS row stride for GEMM staging (bf16): 112B, 16B-aligned
#define OSTR 136  // LDS row stride for epilogue tile (bf16): 272B, 16B-aligned

__device__ __forceinline__ unsigned short f2bf(float f) {
  union { float f; unsigned u; } v; v.f = f;
  unsigned r = v.u + 0x7fffu + ((v.u >> 16) & 1u);
  return (unsigned short)(r >> 16);
}
__device__ __forceinline__ float bf2f(unsigned short u) {
  union { unsigned u; float f; } v; v.u = ((unsigned)u) << 16;
  return v.f;
}

// ---------------- K0: fp32 -> bf16 convert ----------------
__global__ void cvt4_kernel(const float* __restrict__ src,
                            unsigned short* __restrict__ dst, int n4) {
  int i = blockIdx.x * blockDim.x + threadIdx.x;
  int stride = gridDim.x * blockDim.x;
  for (; i < n4; i += stride) {
    float4 v = ((const float4*)src)[i];
    ushort4 o;
    o.x = f2bf(v.x); o.y = f2bf(v.y); o.z = f2bf(v.z); o.w = f2bf(v.w);
    ((ushort4*)dst)[i] = o;
  }
}

// ---------------- K0b: materialize bias table [8][784][784] bf16 ----------------
__global__ void bias_pre_kernel(const float* __restrict__ biases,
                                const int* __restrict__ bias_idxs,
                                unsigned short* __restrict__ bias_tab) {
  int t = blockIdx.x * 256 + threadIdx.x;
  if (t >= NN) return;
  int idx = bias_idxs[t];
  for (int h = 0; h < NH; ++h)
    bias_tab[(size_t)h * NN + t] = f2bf(biases[h * Nseq + idx]);
}

// ---------------- K1: QKV GEMM + BN + LDS-staged coalesced scatter ----------------
__global__ __launch_bounds__(256, 2) void qkv_gemm_kernel(
    const unsigned short* __restrict__ A,
    const unsigned short* __restrict__ Bw,
    const float* __restrict__ gamma, const float* __restrict__ beta,
    const float* __restrict__ mean,  const float* __restrict__ var,
    unsigned short* __restrict__ qo,   // [B,H,N,64] (pre-scaled by 0.125)
    unsigned short* __restrict__ ko,   // [B,H,N,64]
    unsigned short* __restrict__ vto)  // [B,H,256,N]
{
  const int K = DIM;
  __shared__ unsigned short smem[128 * OSTR];
  unsigned short* As = smem;
  unsigned short* Bs = smem + 128 * LSTR;
  int tid = threadIdx.x;
  int wave = tid >> 6, lane = tid & 63;
  int quad = lane >> 4, l16 = lane & 15;
  int wm = wave >> 1, wn = wave & 1;
  int m0 = blockIdx.y * 128, n0 = blockIdx.x * 128;

  floatx4 acc[4][4];
  for (int i = 0; i < 4; ++i)
    for (int j = 0; j < 4; ++j) acc[i][j] = (floatx4)0.0f;

  for (int k0 = 0; k0 < K; k0 += 32) {
    __syncthreads();
    for (int r = 0; r < 2; ++r) {
      int idx = r * 256 + tid;
      int row = idx >> 2;
      int c8 = (idx & 3) << 3;
      *(uint4*)&As[row * LSTR + c8] = *(const uint4*)&A[(size_t)(m0 + row) * K + k0 + c8];
      *(uint4*)&Bs[row * LSTR + c8] = *(const uint4*)&Bw[(size_t)(n0 + row) * K + k0 + c8];
    }
    __syncthreads();
    short8 af[4], bfr[4];
    for (int mt = 0; mt < 4; ++mt)
      af[mt] = *(const short8*)&As[(wm * 64 + mt * 16 + l16) * LSTR + quad * 8];
    for (int nt = 0; nt < 4; ++nt)
      bfr[nt] = *(const short8*)&Bs[(wn * 64 + nt * 16 + l16) * LSTR + quad * 8];
    for (int mt = 0; mt < 4; ++mt)
      for (int nt = 0; nt < 4; ++nt)
        acc[mt][nt] = __builtin_amdgcn_mfma_f32_16x16x32_bf16(af[mt], bfr[nt], acc[mt][nt], 0, 0, 0);
  }

  int tt = n0 % 384;        // 0 => QK tile; 128/256 => V tile
  int h = n0 / 384;
  __syncthreads();

  if (tt == 0) {
    for (int nt = 0; nt < 4; ++nt) {
      int o = n0 + wn * 64 + nt * 16 + l16;
      float sc = gamma[o] * rsqrtf(var[o] + 1e-5f);
      float bb = beta[o] - mean[o] * sc;
      if (wn == 0) { sc *= 0.125f; bb *= 0.125f; }
      int jl = wn * 64 + nt * 16 + l16;
      for (int mt = 0; mt < 4; ++mt)
        for (int r = 0; r < 4; ++r) {
          int ml = wm * 64 + mt * 16 + quad * 4 + r;
          smem[ml * OSTR + jl] = f2bf(acc[mt][nt][r] * sc + bb);
        }
    }
    __syncthreads();
    for (int i = 0; i < 8; ++i) {
      int c = i * 256 + tid;
      int ml = c >> 4, jc = c & 15;
      int m = m0 + ml;
      int b = m / 784, n = m - b * 784;
      uint4 v = *(uint4*)&smem[ml * OSTR + jc * 8];
      int j = jc * 8;
      if (j < 64) *(uint4*)&qo[(((size_t)b * NH + h) * Nseq + n) * KD + j] = v;
      else        *(uint4*)&ko[(((size_t)b * NH + h) * Nseq + n) * KD + (j - 64)] = v;
    }
  } else {
    for (int nt = 0; nt < 4; ++nt) {
      int o = n0 + wn * 64 + nt * 16 + l16;
      float sc = gamma[o] * rsqrtf(var[o] + 1e-5f);
      float bb = beta[o] - mean[o] * sc;
      int cl = wn * 64 + nt * 16 + l16;
      for (int mt = 0; mt < 4; ++mt)
        for (int r = 0; r < 4; ++r) {
          int ml = wm * 64 + mt * 16 + quad * 4 + r;
          smem[cl * OSTR + ml] = f2bf(acc[mt][nt][r] * sc + bb);
        }
    }
    __syncthreads();
    int cbase = tt - 128;
    for (int i = 0; i < 8; ++i) {
      int c = i * 256 + tid;
      int cl = c >> 4, mc = c & 15;
      int m = m0 + mc * 8;
      int b = m / 784, n = m - b * 784;
      uint4 v = *(uint4*)&smem[cl * OSTR + mc * 8];
      *(uint4*)&vto[(((size_t)b * NH + h) * VD + cbase + cl) * Nseq + n] = v;
    }
  }
}

// ---------------- K2: flash attention, software-pipelined, no-max softmax ----------------
// Per kt: [barrier A; regs->LDS; issue prefetch kt+1; lgkm-only barrier B; compute].
// Prefetch is NEVER drained by a barrier (raw s_barrier) — loads fly during compute.
// No online max: |scores| << 88, exp2 cannot overflow fp32 (see round-3 journal).
__global__ __launch_bounds__(256, 2) void attn_kernel(
    const unsigned short* __restrict__ qb,   // [bh][784][64] (pre-scaled by 1/8)
    const unsigned short* __restrict__ kb,   // [bh][784][64]
    const unsigned short* __restrict__ vtb,  // [bh][256][784]
    const unsigned short* __restrict__ bias_tab, // [8][784][784] bf16
    unsigned short* __restrict__ U)          // [16*784*2048] bf16 (post-SiLU)
{
  __shared__ unsigned short vt_lds[256 * 72];   // V^T tile [c][j]
  __shared__ unsigned short k_lds[64 * 72];     // K tile [row][d]
  __shared__ unsigned short ps_lds[4 * 16 * 72];
  int tid = threadIdx.x;
  int wave = tid >> 6, lane = tid & 63;
  int quad = lane >> 4, l16 = lane & 15;

  int L = blockIdx.x;
  int xcd = L & 7;
  int seq = L >> 3;
  int qt = seq % 13;
  int bh = (seq / 13) * 8 + xcd;   // bh % 8 == h == xcd
  int b = bh >> 3, h = bh & 7;
  int row_base = qt * 64 + wave * 16;

  const unsigned short* brow = bias_tab + (size_t)h * NN;

  // Prefetch base pointers (thread-fixed parts)
  const unsigned short* vbase = vtb + ((size_t)bh * VD + (tid >> 3)) * Nseq + ((tid & 7) << 3);
  const unsigned short* kbase = kb + ((size_t)bh * Nseq + (tid >> 2)) * KD + ((tid & 3) << 3);

  int igc[4];
#pragma unroll
  for (int r = 0; r < 4; ++r) {
    int ig = row_base + quad * 4 + r;
    igc[r] = ig < Nseq ? ig : (Nseq - 1);
  }

  // Q A-fragments held in registers all kernel
  short8 qf[2];
  {
    int qrow = row_base + l16;   // OOB (qt=12) reads land in ko region: benign, rows masked at write
    const unsigned short* qp = qb + ((size_t)bh * Nseq + qrow) * KD;
    qf[0] = *(const short8*)(qp + quad * 8);
    qf[1] = *(const short8*)(qp + 32 + quad * 8);
  }

  float lrow[4] = {0.0f, 0.0f, 0.0f, 0.0f};
  floatx4 oacc[16];
#pragma unroll
  for (int ct = 0; ct < 16; ++ct) oacc[ct] = (floatx4)0.0f;

  // ---- prologue prefetch (kt = 0) ----
  uint4 vpre[8], kpre[2];
  unsigned int bpre[16];
#pragma unroll
  for (int rep = 0; rep < 8; ++rep)
    vpre[rep] = *(const uint4*)(vbase + (size_t)rep * 32 * Nseq);
  kpre[0] = *(const uint4*)(kbase);
  kpre[1] = *(const uint4*)(kbase + 32);
#pragma unroll
  for (int r = 0; r < 4; ++r)
#pragma unroll
    for (int jt = 0; jt < 4; ++jt)
      bpre[r * 4 + jt] = brow[(size_t)igc[r] * Nseq + jt * 16 + l16];

  for (int kt = 0; kt < 13; ++kt) {
    // barrier A: all waves done reading LDS of kt-1; also waits our prefetch (long since landed)
    __syncthreads();

    // regs -> LDS
#pragma unroll
    for (int rep = 0; rep < 8; ++rep)
      *(uint4*)&vt_lds[(rep * 32 + (tid >> 3)) * 72 + ((tid & 7) << 3)] = vpre[rep];
    *(uint4*)&k_lds[(tid >> 2) * 72 + ((tid & 3) << 3)] = kpre[0];
    *(uint4*)&k_lds[(tid >> 2) * 72 + ((tid & 3) << 3) + 32] = kpre[1];

    // snapshot bias for this kt before bpre is overwritten
    float btile[16];
#pragma unroll
    for (int i = 0; i < 16; ++i) btile[i] = bf2f((unsigned short)bpre[i]);

    // issue prefetch for kt+1 (in flight during the whole compute phase)
    if (kt < 12) {
      int kn = kt + 1;
#pragma unroll
      for (int rep = 0; rep < 8; ++rep)
        vpre[rep] = *(const uint4*)(vbase + (size_t)rep * 32 * Nseq + kn * 64);
      kpre[0] = *(const uint4*)(kbase + (size_t)kn * 64 * KD);
      kpre[1] = *(const uint4*)(kbase + (size_t)kn * 64 * KD + 32);
#pragma unroll
      for (int r = 0; r < 4; ++r)
#pragma unroll
        for (int jt = 0; jt < 4; ++jt)
          bpre[r * 4 + jt] = brow[(size_t)igc[r] * Nseq + kn * 64 + jt * 16 + l16];
    }

    // barrier B: wait ONLY lgkmcnt(0) (our LDS writes), then raw s_barrier —
    // does NOT drain the in-flight vmcnt prefetch (the m97 barrier trap).
    __builtin_amdgcn_s_waitcnt(0xC07F);
    __builtin_amdgcn_s_barrier();

    // S = q K^T from LDS
    floatx4 s4[4];
#pragma unroll
    for (int jt = 0; jt < 4; ++jt) {
      short8 kf0 = *(const short8*)&k_lds[(jt * 16 + l16) * 72 + quad * 8];
      short8 kf1 = *(const short8*)&k_lds[(jt * 16 + l16) * 72 + quad * 8 + 32];
      s4[jt] = (floatx4)0.0f;
      s4[jt] = __builtin_amdgcn_mfma_f32_16x16x32_bf16(qf[0], kf0, s4[jt], 0, 0, 0);
      s4[jt] = __builtin_amdgcn_mfma_f32_16x16x32_bf16(qf[1], kf1, s4[jt], 0, 0, 0);
    }

    // no-max softmax: p = exp2(s*log2e); tail kt only jt==0 is valid
    bool tail = (kt == 12);
#pragma unroll
    for (int jt = 0; jt < 4; ++jt)
#pragma unroll
      for (int r = 0; r < 4; ++r) {
        float s = s4[jt][r] + btile[r * 4 + jt];
        float p = exp2f(s * 1.44269504f);
        if (tail && jt > 0) p = 0.0f;
        s4[jt][r] = p;
        lrow[r] += p;
      }

    // P -> LDS (C-layout -> A-layout; per-wave region, intra-wave dep only)
#pragma unroll
    for (int jt = 0; jt < 4; ++jt)
#pragma unroll
      for (int r = 0; r < 4; ++r)
        ps_lds[wave * 1152 + (quad * 4 + r) * 72 + jt * 16 + l16] = f2bf(s4[jt][r]);

    // O += P V
#pragma unroll
    for (int ks = 0; ks < 2; ++ks) {
      short8 pf = *(const short8*)&ps_lds[wave * 1152 + l16 * 72 + ks * 32 + quad * 8];
#pragma unroll
      for (int ct = 0; ct < 16; ++ct) {
        short8 vf = *(const short8*)&vt_lds[(ct * 16 + l16) * 72 + ks * 32 + quad * 8];
        oacc[ct] = __builtin_amdgcn_mfma_f32_16x16x32_bf16(pf, vf, oacc[ct], 0, 0, 0);
      }
    }
  }

  // epilogue: reduce l across 16-lane group, normalize, SiLU, write U
  float inv[4];
#pragma unroll
  for (int r = 0; r < 4; ++r) {
    float tot = lrow[r];
    for (int off = 1; off < 16; off <<= 1) tot += __shfl_xor(tot, off);
    inv[r] = 1.0f / tot;
  }
#pragma unroll
  for (int r = 0; r < 4; ++r) {
    int ig = row_base + quad * 4 + r;
    if (ig >= Nseq) continue;
    size_t base = ((size_t)b * Nseq + ig) * HV + h * VD;
#pragma unroll
    for (int ct = 0; ct < 16; ++ct) {
      float u = oacc[ct][r] * inv[r];
      float sg = 1.0f / (1.0f + exp2f(-u * 1.44269504f));
      U[base + ct * 16 + l16] = f2bf(u * sg);
    }
  }
}

// ---------------- K3: proj GEMM (operand-swapped) + BN -> fp32 out ----------------
__global__ __launch_bounds__(256, 2) void proj_gemm_kernel(
    const unsigned short* __restrict__ Ubuf,  // [12544][2048]
    const unsigned short* __restrict__ Wp,    // [512][2048]
    const float* __restrict__ gamma, const float* __restrict__ beta,
    const float* __restrict__ mean,  const float* __restrict__ var,
    float* __restrict__ out)                  // [12544][512]
{
  const int K = HV;
  __shared__ unsigned short As[128 * LSTR];
  __shared__ unsigned short Bs[128 * LSTR];
  int tid = threadIdx.x;
  int wave = tid >> 6, lane = tid & 63;
  int quad = lane >> 4, l16 = lane & 15;
  int wm = wave >> 1, wn = wave & 1;
  int o0 = blockIdx.y * 128, mB = blockIdx.x * 128;

  floatx4 acc[4][4];
  for (int i = 0; i < 4; ++i)
    for (int j = 0; j < 4; ++j) acc[i][j] = (floatx4)0.0f;

  for (int k0 = 0; k0 < K; k0 += 32) {
    __syncthreads();
    for (int r = 0; r < 2; ++r) {
      int idx = r * 256 + tid;
      int row = idx >> 2;
      int c8 = (idx & 3) << 3;
      *(uint4*)&As[row * LSTR + c8] = *(const uint4*)&Wp[(size_t)(o0 + row) * K + k0 + c8];
      *(uint4*)&Bs[row * LSTR + c8] = *(const uint4*)&Ubuf[(size_t)(mB + row) * K + k0 + c8];
    }
    __syncthreads();
    short8 af[4], bfr[4];
    for (int mt = 0; mt < 4; ++mt)
      af[mt] = *(const short8*)&As[(wm * 64 + mt * 16 + l16) * LSTR + quad * 8];
    for (int nt = 0; nt < 4; ++nt)
      bfr[nt] = *(const short8*)&Bs[(wn * 64 + nt * 16 + l16) * LSTR + quad * 8];
    for (int mt = 0; mt < 4; ++mt)
      for (int nt = 0; nt < 4; ++nt)
        acc[mt][nt] = __builtin_amdgcn_mfma_f32_16x16x32_bf16(af[mt], bfr[nt], acc[mt][nt], 0, 0, 0);
  }

  for (int mt = 0; mt < 4; ++mt) {
    int ob = o0 + wm * 64 + mt * 16 + quad * 4;
    float4 g = *(const float4*)&gamma[ob];
    float4 vr = *(const float4*)&var[ob];
    float4 mn = *(const float4*)&mean[ob];
    float4 bt = *(const float4*)&beta[ob];
    float sc0 = g.x * rsqrtf(vr.x + 1e-5f), bb0 = bt.x - mn.x * sc0;
    float sc1 = g.y * rsqrtf(vr.y + 1e-5f), bb1 = bt.y - mn.y * sc1;
    float sc2 = g.z * rsqrtf(vr.z + 1e-5f), bb2 = bt.z - mn.z * sc2;
    float sc3 = g.w * rsqrtf(vr.w + 1e-5f), bb3 = bt.w - mn.w * sc3;
    for (int nt = 0; nt < 4; ++nt) {
      int m = mB + wn * 64 + nt * 16 + l16;
      float4 v;
      v.x = acc[mt][nt][0] * sc0 + bb0;
      v.y = acc[mt][nt][1] * sc1 + bb1;
      v.z = acc[mt][nt][2] * sc2 + bb2;
      v.w = acc[mt][nt][3] * sc3 + bb3;
      *(float4*)&out[(size_t)m * DIM + ob] = v;
    }
  }
}

// ---------------- launch ----------------
extern "C" void kernel_launch(void* const* d_in, const int* in_sizes, int n_in,
                              void* d_out, int out_size, void* d_ws, size_t ws_size,
                              hipStream_t stream) {
  const float* x          = (const float*)d_in[0];
  const float* qkv_w      = (const float*)d_in[1];
  const float* qkv_gamma  = (const float*)d_in[2];
  const float* qkv_beta   = (const float*)d_in[3];
  const float* qkv_mean   = (const float*)d_in[4];
  const float* qkv_var    = (const float*)d_in[5];
  const float* att_biases = (const float*)d_in[6];
  const float* proj_w     = (const float*)d_in[7];
  const float* proj_gamma = (const float*)d_in[8];
  const float* proj_beta  = (const float*)d_in[9];
  const float* proj_mean  = (const float*)d_in[10];
  const float* proj_var   = (const float*)d_in[11];
  const int*   bias_idxs  = (const int*)d_in[12];
  float* out = (float*)d_out;

  char* ws = (char*)d_ws;
  unsigned short* xb  = (unsigned short*)(ws);                 // 12544*512 (12.85 MB)
  unsigned short* bias_tab = (unsigned short*)(ws);            // 8*784*784 bf16 — aliases xb (dead after qkv_gemm)
  unsigned short* wq  = (unsigned short*)(ws + 12845056);      // 3072*512
  unsigned short* wp  = (unsigned short*)(ws + 15990784);      // 512*2048
  unsigned short* qo  = (unsigned short*)(ws + 18087936);      // 16*8*784*64
  unsigned short* ko  = (unsigned short*)(ws + 30932992);      // 16*8*784*64
  unsigned short* vto = (unsigned short*)(ws + 43778048);      // 16*8*256*784
  unsigned short* Ub  = (unsigned short*)(ws + 95158272);      // 12544*2048
  // total: 146538496 bytes

  {
    int n4 = (Bsz * Nseq * DIM) / 4;
    cvt4_kernel<<<(n4 + 255) / 256, 256, 0, stream>>>(x, xb, n4);
  }
  {
    int n4 = (QKV_OUT * DIM) / 4;
    cvt4_kernel<<<(n4 + 255) / 256, 256, 0, stream>>>(qkv_w, wq, n4);
  }
  {
    int n4 = (DIM * HV) / 4;
    cvt4_kernel<<<(n4 + 255) / 256, 256, 0, stream>>>(proj_w, wp, n4);
  }

  qkv_gemm_kernel<<<dim3(QKV_OUT / 128, (Bsz * Nseq) / 128), 256, 0, stream>>>(
      xb, wq, qkv_gamma, qkv_beta, qkv_mean, qkv_var, qo, ko, vto);

  bias_pre_kernel<<<(NN + 255) / 256, 256, 0, stream>>>(att_biases, bias_idxs, bias_tab);

  attn_kernel<<<13 * Bsz * NH, 256, 0, stream>>>(qo, ko, vto, bias_tab, Ub);

  proj_gemm_kernel<<<dim3((Bsz * Nseq) / 128, DIM / 128), 256, 0, stream>>>(
      Ub, wp, proj_gamma, proj_beta, proj_mean, proj_var, out);
}

// Round 5
// 395.052 us; speedup vs baseline: 2.7536x; 1.2671x over previous
//
#include <hip/hip_runtime.h>

// Problem constants
#define Bsz 16
#define Nseq 784
#define DIM 512
#define NH 8
#define KD 64
#define VD 256
#define QKV_OUT 3072   // (2*64+256)*8
#define HV 2048        // NH*VD
#define NN 614656      // 784*784

typedef __attribute__((ext_vector_type(8))) short short8;
typedef __attribute__((ext_vector_type(4))) float floatx4;

#define LSTR 56   // LDS row stride for GEMM staging (bf16): 112B, 16B-aligned
#define OSTR 136  // LDS row stride for epilogue tile (bf16): 272B, 16B-aligned

__device__ __forceinline__ unsigned short f2bf(float f) {
  union { float f; unsigned u; } v; v.f = f;
  unsigned r = v.u + 0x7fffu + ((v.u >> 16) & 1u);
  return (unsigned short)(r >> 16);
}
__device__ __forceinline__ float bf2f(unsigned short u) {
  union { unsigned u; float f; } v; v.u = ((unsigned)u) << 16;
  return v.f;
}

// async global->LDS, 16B per lane; LDS dst = base + lane*16 (wave-uniform base)
__device__ __forceinline__ void glds16(const unsigned short* g, unsigned short* l) {
  __builtin_amdgcn_global_load_lds(
      (const __attribute__((address_space(1))) void*)g,
      (__attribute__((address_space(3))) void*)l, 16, 0, 0);
}

// ---------------- K0: fp32 -> bf16 convert ----------------
__global__ void cvt4_kernel(const float* __restrict__ src,
                            unsigned short* __restrict__ dst, int n4) {
  int i = blockIdx.x * blockDim.x + threadIdx.x;
  int stride = gridDim.x * blockDim.x;
  for (; i < n4; i += stride) {
    float4 v = ((const float4*)src)[i];
    ushort4 o;
    o.x = f2bf(v.x); o.y = f2bf(v.y); o.z = f2bf(v.z); o.w = f2bf(v.w);
    ((ushort4*)dst)[i] = o;
  }
}

// ---------------- K0b: materialize bias table [8][784][784] bf16 ----------------
__global__ void bias_pre_kernel(const float* __restrict__ biases,
                                const int* __restrict__ bias_idxs,
                                unsigned short* __restrict__ bias_tab) {
  int t = blockIdx.x * 256 + threadIdx.x;
  if (t >= NN) return;
  int idx = bias_idxs[t];
  for (int h = 0; h < NH; ++h)
    bias_tab[(size_t)h * NN + t] = f2bf(biases[h * Nseq + idx]);
}

// ---------------- K1: QKV GEMM + BN + LDS-staged coalesced scatter ----------------
__global__ __launch_bounds__(256, 2) void qkv_gemm_kernel(
    const unsigned short* __restrict__ A,
    const unsigned short* __restrict__ Bw,
    const float* __restrict__ gamma, const float* __restrict__ beta,
    const float* __restrict__ mean,  const float* __restrict__ var,
    unsigned short* __restrict__ qo,   // [B,H,N,64] (pre-scaled by 0.125)
    unsigned short* __restrict__ ko,   // [B,H,N,64]
    unsigned short* __restrict__ vto)  // [B,H,256,N]
{
  const int K = DIM;
  __shared__ unsigned short smem[128 * OSTR];
  unsigned short* As = smem;
  unsigned short* Bs = smem + 128 * LSTR;
  int tid = threadIdx.x;
  int wave = tid >> 6, lane = tid & 63;
  int quad = lane >> 4, l16 = lane & 15;
  int wm = wave >> 1, wn = wave & 1;
  int m0 = blockIdx.y * 128, n0 = blockIdx.x * 128;

  floatx4 acc[4][4];
  for (int i = 0; i < 4; ++i)
    for (int j = 0; j < 4; ++j) acc[i][j] = (floatx4)0.0f;

  for (int k0 = 0; k0 < K; k0 += 32) {
    __syncthreads();
    for (int r = 0; r < 2; ++r) {
      int idx = r * 256 + tid;
      int row = idx >> 2;
      int c8 = (idx & 3) << 3;
      *(uint4*)&As[row * LSTR + c8] = *(const uint4*)&A[(size_t)(m0 + row) * K + k0 + c8];
      *(uint4*)&Bs[row * LSTR + c8] = *(const uint4*)&Bw[(size_t)(n0 + row) * K + k0 + c8];
    }
    __syncthreads();
    short8 af[4], bfr[4];
    for (int mt = 0; mt < 4; ++mt)
      af[mt] = *(const short8*)&As[(wm * 64 + mt * 16 + l16) * LSTR + quad * 8];
    for (int nt = 0; nt < 4; ++nt)
      bfr[nt] = *(const short8*)&Bs[(wn * 64 + nt * 16 + l16) * LSTR + quad * 8];
    for (int mt = 0; mt < 4; ++mt)
      for (int nt = 0; nt < 4; ++nt)
        acc[mt][nt] = __builtin_amdgcn_mfma_f32_16x16x32_bf16(af[mt], bfr[nt], acc[mt][nt], 0, 0, 0);
  }

  int tt = n0 % 384;        // 0 => QK tile; 128/256 => V tile
  int h = n0 / 384;
  __syncthreads();

  if (tt == 0) {
    for (int nt = 0; nt < 4; ++nt) {
      int o = n0 + wn * 64 + nt * 16 + l16;
      float sc = gamma[o] * rsqrtf(var[o] + 1e-5f);
      float bb = beta[o] - mean[o] * sc;
      if (wn == 0) { sc *= 0.125f; bb *= 0.125f; }
      int jl = wn * 64 + nt * 16 + l16;
      for (int mt = 0; mt < 4; ++mt)
        for (int r = 0; r < 4; ++r) {
          int ml = wm * 64 + mt * 16 + quad * 4 + r;
          smem[ml * OSTR + jl] = f2bf(acc[mt][nt][r] * sc + bb);
        }
    }
    __syncthreads();
    for (int i = 0; i < 8; ++i) {
      int c = i * 256 + tid;
      int ml = c >> 4, jc = c & 15;
      int m = m0 + ml;
      int b = m / 784, n = m - b * 784;
      uint4 v = *(uint4*)&smem[ml * OSTR + jc * 8];
      int j = jc * 8;
      if (j < 64) *(uint4*)&qo[(((size_t)b * NH + h) * Nseq + n) * KD + j] = v;
      else        *(uint4*)&ko[(((size_t)b * NH + h) * Nseq + n) * KD + (j - 64)] = v;
    }
  } else {
    for (int nt = 0; nt < 4; ++nt) {
      int o = n0 + wn * 64 + nt * 16 + l16;
      float sc = gamma[o] * rsqrtf(var[o] + 1e-5f);
      float bb = beta[o] - mean[o] * sc;
      int cl = wn * 64 + nt * 16 + l16;
      for (int mt = 0; mt < 4; ++mt)
        for (int r = 0; r < 4; ++r) {
          int ml = wm * 64 + mt * 16 + quad * 4 + r;
          smem[cl * OSTR + ml] = f2bf(acc[mt][nt][r] * sc + bb);
        }
    }
    __syncthreads();
    int cbase = tt - 128;
    for (int i = 0; i < 8; ++i) {
      int c = i * 256 + tid;
      int cl = c >> 4, mc = c & 15;
      int m = m0 + mc * 8;
      int b = m / 784, n = m - b * 784;
      uint4 v = *(uint4*)&smem[cl * OSTR + mc * 8];
      *(uint4*)&vto[(((size_t)b * NH + h) * VD + cbase + cl) * Nseq + n] = v;
    }
  }
}

// ---------------- K2: flash attention, glds double-buffered pipeline ----------------
// Two sibling blocks per (bh,qt): each handles 128 V-channels (QK duplicated).
// Per kt: [lgkm-wait; s_barrier A] -> issue 8 async glds for kt+1 (V4,K2,bias2)
// -> [vmcnt(8); s_barrier B] -> compute. Prefetch never drained (no __syncthreads).
// LDS rows are unpadded 64-elem; 16B chunks XOR-swizzled (phys = ch ^ (row&7)):
// 2-way bank alias only on both glds-store and ds_read_b128 sides.
// No online max (|s| << 88 cannot overflow exp2; verified round 3->4).
__global__ __launch_bounds__(256, 2) void attn_kernel(
    const unsigned short* __restrict__ qb,   // [bh][784][64] (pre-scaled by 1/8)
    const unsigned short* __restrict__ kb,   // [bh][784][64]
    const unsigned short* __restrict__ vtb,  // [bh][256][784]
    const unsigned short* __restrict__ bias_tab, // [8][784][784] bf16
    unsigned short* __restrict__ U)          // [16*784*2048] bf16 (post-SiLU)
{
  __shared__ unsigned short vt_lds[2 * 128 * 64];  // 32 KB: V^T half-tile, dbuf, swizzled
  __shared__ unsigned short k_lds[2 * 64 * 64];    // 16 KB: K tile, dbuf, swizzled
  __shared__ unsigned short bs_lds[2 * 64 * 64];   // 16 KB: bias tile, dbuf, swizzled
  __shared__ unsigned short ps_lds[4 * 16 * 72];   //  9 KB: per-wave P strip
  int tid = threadIdx.x;
  int wave = tid >> 6, lane = tid & 63;
  int quad = lane >> 4, l16 = lane & 15;

  int L = blockIdx.x;
  int xcd = L & 7;
  int s = L >> 3;
  int vh = s & 1;                  // which half of VD
  int s2 = s >> 1;
  int qt = s2 % 13;
  int bh = (s2 / 13) * 8 + xcd;    // bh % 8 == h == xcd
  int b = bh >> 3, h = bh & 7;
  int row_base = qt * 64 + wave * 16;

  const unsigned short* brow = bias_tab + (size_t)h * NN;

  // glds lane mapping: lane covers (row-sub lc, swizzled chunk lch)
  int lc = lane >> 3;              // 0..7
  int lch = (lane & 7) ^ lc;       // logical 16B chunk this lane fetches
  int sw = l16 & 7;                // read-side swizzle key

  // Per-instr source bases (elems), kt term added in loop
  const unsigned short* vsrc[4];
#pragma unroll
  for (int t = 0; t < 4; ++t)
    vsrc[t] = vtb + ((size_t)bh * VD + vh * 128 + wave * 32 + t * 8 + lc) * Nseq + lch * 8;
  const unsigned short* ksrc[2];
#pragma unroll
  for (int t = 0; t < 2; ++t)
    ksrc[t] = kb + (size_t)bh * (Nseq * KD) + (wave * 16 + t * 8 + lc) * KD + lch * 8;
  const unsigned short* bsrc[2];
#pragma unroll
  for (int t = 0; t < 2; ++t) {
    int ig = qt * 64 + wave * 16 + t * 8 + lc;
    if (ig > Nseq - 1) ig = Nseq - 1;   // clamp dead rows
    bsrc[t] = brow + (size_t)ig * Nseq + lch * 8;
  }

  // ---- prologue: issue tile 0 (8 glds) ----
#pragma unroll
  for (int t = 0; t < 4; ++t)
    glds16(vsrc[t], &vt_lds[(wave * 4 + t) * 512]);
#pragma unroll
  for (int t = 0; t < 2; ++t)
    glds16(ksrc[t], &k_lds[(wave * 2 + t) * 512]);
#pragma unroll
  for (int t = 0; t < 2; ++t)
    glds16(bsrc[t], &bs_lds[(wave * 2 + t) * 512]);

  // Q A-fragments (after glds issue so tile-0 loads are oldest-or-equal in queue)
  short8 qf[2];
  {
    int qrow = row_base + l16;   // OOB (qt=12) reads land in ko region: benign, rows masked at write
    const unsigned short* qp = qb + ((size_t)bh * Nseq + qrow) * KD;
    qf[0] = *(const short8*)(qp + quad * 8);
    qf[1] = *(const short8*)(qp + 32 + quad * 8);
  }

  float lrow[4] = {0.0f, 0.0f, 0.0f, 0.0f};
  floatx4 oacc[8];
#pragma unroll
  for (int ct = 0; ct < 8; ++ct) oacc[ct] = (floatx4)0.0f;

  for (int kt = 0; kt < 13; ++kt) {
    int cur = kt & 1;
    int nb = cur ^ 1;
    // barrier A: all waves finished compute(kt-1) -> buf nb is free to overwrite
    __builtin_amdgcn_s_waitcnt(0xC07F);   // lgkmcnt(0) only
    __builtin_amdgcn_s_barrier();

    // issue 8 async glds for tile kt+1 (wrapped at 12->0 to keep vmcnt uniform)
    int ktn = kt + 1; if (ktn >= 13) ktn = 0;
#pragma unroll
    for (int t = 0; t < 4; ++t)
      glds16(vsrc[t] + ktn * 64, &vt_lds[nb * 8192 + (wave * 4 + t) * 512]);
#pragma unroll
    for (int t = 0; t < 2; ++t)
      glds16(ksrc[t] + (size_t)ktn * 4096, &k_lds[nb * 4096 + (wave * 2 + t) * 512]);
#pragma unroll
    for (int t = 0; t < 2; ++t)
      glds16(bsrc[t] + ktn * 64, &bs_lds[nb * 4096 + (wave * 2 + t) * 512]);

    // barrier B: tile(kt)'s 8 glds (issued last iter) landed; kt+1's 8 stay in flight
    __builtin_amdgcn_s_waitcnt(0x0F78);   // vmcnt(8), no lgkm/exp wait
    __builtin_amdgcn_s_barrier();

    const unsigned short* kbuf = &k_lds[cur * 4096];
    const unsigned short* vbuf = &vt_lds[cur * 8192];
    const unsigned short* bbuf = &bs_lds[cur * 4096];

    // S = q K^T from swizzled LDS
    floatx4 s4[4];
#pragma unroll
    for (int jt = 0; jt < 4; ++jt) {
      int row = jt * 16 + l16;
      short8 kf0 = *(const short8*)&kbuf[row * 64 + (quad ^ sw) * 8];
      short8 kf1 = *(const short8*)&kbuf[row * 64 + ((quad + 4) ^ sw) * 8];
      s4[jt] = (floatx4)0.0f;
      s4[jt] = __builtin_amdgcn_mfma_f32_16x16x32_bf16(qf[0], kf0, s4[jt], 0, 0, 0);
      s4[jt] = __builtin_amdgcn_mfma_f32_16x16x32_bf16(qf[1], kf1, s4[jt], 0, 0, 0);
    }

    // bias (from swizzled LDS tile) + no-max softmax
    bool tail = (kt == 12);
#pragma unroll
    for (int r = 0; r < 4; ++r) {
      int lr = wave * 16 + quad * 4 + r;
      int lr7 = lr & 7;
#pragma unroll
      for (int jt = 0; jt < 4; ++jt) {
        int chunk = jt * 2 + (l16 >> 3);
        float bt = bf2f(bbuf[lr * 64 + (chunk ^ lr7) * 8 + sw]);
        float p = exp2f((s4[jt][r] + bt) * 1.44269504f);
        if (tail && jt > 0) p = 0.0f;
        s4[jt][r] = p;
        lrow[r] += p;
      }
    }

    // P -> LDS (C-layout -> A-layout; per-wave region)
#pragma unroll
    for (int jt = 0; jt < 4; ++jt)
#pragma unroll
      for (int r = 0; r < 4; ++r)
        ps_lds[wave * 1152 + (quad * 4 + r) * 72 + jt * 16 + l16] = f2bf(s4[jt][r]);

    // O += P V (8 col-tiles: this block's 128-channel half)
#pragma unroll
    for (int ks = 0; ks < 2; ++ks) {
      short8 pf = *(const short8*)&ps_lds[wave * 1152 + l16 * 72 + ks * 32 + quad * 8];
#pragma unroll
      for (int ct = 0; ct < 8; ++ct) {
        int c = ct * 16 + l16;
        short8 vf = *(const short8*)&vbuf[c * 64 + ((ks * 4 + quad) ^ sw) * 8];
        oacc[ct] = __builtin_amdgcn_mfma_f32_16x16x32_bf16(pf, vf, oacc[ct], 0, 0, 0);
      }
    }
  }

  // drain remaining async glds before LDS goes out of scope
  __builtin_amdgcn_s_waitcnt(0x0070);   // vmcnt(0) + lgkmcnt(0)

  // epilogue: reduce l across 16-lane group, normalize, SiLU, write U half
  float inv[4];
#pragma unroll
  for (int r = 0; r < 4; ++r) {
    float tot = lrow[r];
    for (int off = 1; off < 16; off <<= 1) tot += __shfl_xor(tot, off);
    inv[r] = 1.0f / tot;
  }
#pragma unroll
  for (int r = 0; r < 4; ++r) {
    int ig = row_base + quad * 4 + r;
    if (ig >= Nseq) continue;
    size_t base = ((size_t)b * Nseq + ig) * HV + h * VD + vh * 128;
#pragma unroll
    for (int ct = 0; ct < 8; ++ct) {
      float u = oacc[ct][r] * inv[r];
      float sg = 1.0f / (1.0f + exp2f(-u * 1.44269504f));
      U[base + ct * 16 + l16] = f2bf(u * sg);
    }
  }
}

// ---------------- K3: proj GEMM (operand-swapped) + BN -> fp32 out ----------------
__global__ __launch_bounds__(256, 2) void proj_gemm_kernel(
    const unsigned short* __restrict__ Ubuf,  // [12544][2048]
    const unsigned short* __restrict__ Wp,    // [512][2048]
    const float* __restrict__ gamma, const float* __restrict__ beta,
    const float* __restrict__ mean,  const float* __restrict__ var,
    float* __restrict__ out)                  // [12544][512]
{
  const int K = HV;
  __shared__ unsigned short As[128 * LSTR];
  __shared__ unsigned short Bs[128 * LSTR];
  int tid = threadIdx.x;
  int wave = tid >> 6, lane = tid & 63;
  int quad = lane >> 4, l16 = lane & 15;
  int wm = wave >> 1, wn = wave & 1;
  int o0 = blockIdx.y * 128, mB = blockIdx.x * 128;

  floatx4 acc[4][4];
  for (int i = 0; i < 4; ++i)
    for (int j = 0; j < 4; ++j) acc[i][j] = (floatx4)0.0f;

  for (int k0 = 0; k0 < K; k0 += 32) {
    __syncthreads();
    for (int r = 0; r < 2; ++r) {
      int idx = r * 256 + tid;
      int row = idx >> 2;
      int c8 = (idx & 3) << 3;
      *(uint4*)&As[row * LSTR + c8] = *(const uint4*)&Wp[(size_t)(o0 + row) * K + k0 + c8];
      *(uint4*)&Bs[row * LSTR + c8] = *(const uint4*)&Ubuf[(size_t)(mB + row) * K + k0 + c8];
    }
    __syncthreads();
    short8 af[4], bfr[4];
    for (int mt = 0; mt < 4; ++mt)
      af[mt] = *(const short8*)&As[(wm * 64 + mt * 16 + l16) * LSTR + quad * 8];
    for (int nt = 0; nt < 4; ++nt)
      bfr[nt] = *(const short8*)&Bs[(wn * 64 + nt * 16 + l16) * LSTR + quad * 8];
    for (int mt = 0; mt < 4; ++mt)
      for (int nt = 0; nt < 4; ++nt)
        acc[mt][nt] = __builtin_amdgcn_mfma_f32_16x16x32_bf16(af[mt], bfr[nt], acc[mt][nt], 0, 0, 0);
  }

  for (int mt = 0; mt < 4; ++mt) {
    int ob = o0 + wm * 64 + mt * 16 + quad * 4;
    float4 g = *(const float4*)&gamma[ob];
    float4 vr = *(const float4*)&var[ob];
    float4 mn = *(const float4*)&mean[ob];
    float4 bt = *(const float4*)&beta[ob];
    float sc0 = g.x * rsqrtf(vr.x + 1e-5f), bb0 = bt.x - mn.x * sc0;
    float sc1 = g.y * rsqrtf(vr.y + 1e-5f), bb1 = bt.y - mn.y * sc1;
    float sc2 = g.z * rsqrtf(vr.z + 1e-5f), bb2 = bt.z - mn.z * sc2;
    float sc3 = g.w * rsqrtf(vr.w + 1e-5f), bb3 = bt.w - mn.w * sc3;
    for (int nt = 0; nt < 4; ++nt) {
      int m = mB + wn * 64 + nt * 16 + l16;
      float4 v;
      v.x = acc[mt][nt][0] * sc0 + bb0;
      v.y = acc[mt][nt][1] * sc1 + bb1;
      v.z = acc[mt][nt][2] * sc2 + bb2;
      v.w = acc[mt][nt][3] * sc3 + bb3;
      *(float4*)&out[(size_t)m * DIM + ob] = v;
    }
  }
}

// ---------------- launch ----------------
extern "C" void kernel_launch(void* const* d_in, const int* in_sizes, int n_in,
                              void* d_out, int out_size, void* d_ws, size_t ws_size,
                              hipStream_t stream) {
  const float* x          = (const float*)d_in[0];
  const float* qkv_w      = (const float*)d_in[1];
  const float* qkv_gamma  = (const float*)d_in[2];
  const float* qkv_beta   = (const float*)d_in[3];
  const float* qkv_mean   = (const float*)d_in[4];
  const float* qkv_var    = (const float*)d_in[5];
  const float* att_biases = (const float*)d_in[6];
  const float* proj_w     = (const float*)d_in[7];
  const float* proj_gamma = (const float*)d_in[8];
  const float* proj_beta  = (const float*)d_in[9];
  const float* proj_mean  = (const float*)d_in[10];
  const float* proj_var   = (const float*)d_in[11];
  const int*   bias_idxs  = (const int*)d_in[12];
  float* out = (float*)d_out;

  char* ws = (char*)d_ws;
  unsigned short* xb  = (unsigned short*)(ws);                 // 12544*512 (12.85 MB)
  unsigned short* bias_tab = (unsigned short*)(ws);            // 8*784*784 bf16 — aliases xb (dead after qkv_gemm)
  unsigned short* wq  = (unsigned short*)(ws + 12845056);      // 3072*512
  unsigned short* wp  = (unsigned short*)(ws + 15990784);      // 512*2048
  unsigned short* qo  = (unsigned short*)(ws + 18087936);      // 16*8*784*64
  unsigned short* ko  = (unsigned short*)(ws + 30932992);      // 16*8*784*64
  unsigned short* vto = (unsigned short*)(ws + 43778048);      // 16*8*256*784
  unsigned short* Ub  = (unsigned short*)(ws + 95158272);      // 12544*2048
  // total: 146538496 bytes

  {
    int n4 = (Bsz * Nseq * DIM) / 4;
    cvt4_kernel<<<(n4 + 255) / 256, 256, 0, stream>>>(x, xb, n4);
  }
  {
    int n4 = (QKV_OUT * DIM) / 4;
    cvt4_kernel<<<(n4 + 255) / 256, 256, 0, stream>>>(qkv_w, wq, n4);
  }
  {
    int n4 = (DIM * HV) / 4;
    cvt4_kernel<<<(n4 + 255) / 256, 256, 0, stream>>>(proj_w, wp, n4);
  }

  qkv_gemm_kernel<<<dim3(QKV_OUT / 128, (Bsz * Nseq) / 128), 256, 0, stream>>>(
      xb, wq, qkv_gamma, qkv_beta, qkv_mean, qkv_var, qo, ko, vto);

  bias_pre_kernel<<<(NN + 255) / 256, 256, 0, stream>>>(att_biases, bias_idxs, bias_tab);

  attn_kernel<<<13 * 2 * Bsz * NH, 256, 0, stream>>>(qo, ko, vto, bias_tab, Ub);

  proj_gemm_kernel<<<dim3((Bsz * Nseq) / 128, DIM / 128), 256, 0, stream>>>(
      Ub, wp, proj_gamma, proj_beta, proj_mean, proj_var, out);
}

// Round 6
// 366.249 us; speedup vs baseline: 2.9702x; 1.0786x over previous
//
#include <hip/hip_runtime.h>

// Problem constants
#define Bsz 16
#define Nseq 784
#define DIM 512
#define NH 8
#define KD 64
#define VD 256
#define QKV_OUT 3072   // (2*64+256)*8
#define HV 2048        // NH*VD
#define NN 614656      // 784*784

typedef __attribute__((ext_vector_type(8))) short short8;
typedef __attribute__((ext_vector_type(4))) float floatx4;

#define OSTR 136  // LDS row stride for qkv epilogue tile (bf16): 272B, 16B-aligned

#if __has_builtin(__builtin_amdgcn_exp2f)
#define EXP2(x) __builtin_amdgcn_exp2f(x)
#else
#define EXP2(x) exp2f(x)
#endif

__device__ __forceinline__ unsigned short f2bf(float f) {
  union { float f; unsigned u; } v; v.f = f;
  unsigned r = v.u + 0x7fffu + ((v.u >> 16) & 1u);
  return (unsigned short)(r >> 16);
}
__device__ __forceinline__ float bf2f(unsigned short u) {
  union { unsigned u; float f; } v; v.u = ((unsigned)u) << 16;
  return v.f;
}

// async global->LDS, 16B per lane; LDS dst = wave-uniform base + lane*16
__device__ __forceinline__ void glds16(const unsigned short* g, unsigned short* l) {
  __builtin_amdgcn_global_load_lds(
      (const __attribute__((address_space(1))) void*)g,
      (__attribute__((address_space(3))) void*)l, 16, 0, 0);
}

// ---------------- K0: fused fp32 -> bf16 convert (x, qkv_w, proj_w) ----------------
#define N4X 1605632   // x float4s
#define N4Q 393216    // qkv_w float4s
#define N4P 262144    // proj_w float4s
__global__ void cvt_all_kernel(const float* __restrict__ x,
                               const float* __restrict__ qw,
                               const float* __restrict__ pw,
                               unsigned short* __restrict__ xb,
                               unsigned short* __restrict__ wq,
                               unsigned short* __restrict__ wp) {
  int i = blockIdx.x * 256 + threadIdx.x;
  const float4* s; ushort4* d; int off;
  if (i < N4X)              { s = (const float4*)x;  d = (ushort4*)xb; off = i; }
  else if (i < N4X + N4Q)   { s = (const float4*)qw; d = (ushort4*)wq; off = i - N4X; }
  else if (i < N4X + N4Q + N4P) { s = (const float4*)pw; d = (ushort4*)wp; off = i - N4X - N4Q; }
  else return;
  float4 v = s[off];
  ushort4 o;
  o.x = f2bf(v.x); o.y = f2bf(v.y); o.z = f2bf(v.z); o.w = f2bf(v.w);
  d[off] = o;
}

// ---------------- K0b: materialize bias table [8][784][784] bf16 ----------------
__global__ void bias_pre_kernel(const float* __restrict__ biases,
                                const int* __restrict__ bias_idxs,
                                unsigned short* __restrict__ bias_tab) {
  int t = blockIdx.x * 256 + threadIdx.x;
  if (t >= NN) return;
  int idx = bias_idxs[t];
  for (int h = 0; h < NH; ++h)
    bias_tab[(size_t)h * NN + t] = f2bf(biases[h * Nseq + idx]);
}

// ---------------- K1: QKV GEMM (glds staging) + BN + LDS-staged scatter ----------------
__global__ __launch_bounds__(256, 2) void qkv_gemm_kernel(
    const unsigned short* __restrict__ A,
    const unsigned short* __restrict__ Bw,
    const float* __restrict__ gamma, const float* __restrict__ beta,
    const float* __restrict__ mean,  const float* __restrict__ var,
    unsigned short* __restrict__ qo,   // [B,H,N,64] (pre-scaled by 0.125)
    unsigned short* __restrict__ ko,   // [B,H,N,64]
    unsigned short* __restrict__ vto)  // [B,H,256,N]
{
  const int K = DIM;
  __shared__ unsigned short smem[128 * OSTR];  // 34816B; staging uses first 16KB
  unsigned short* As = smem;                   // [128][32] unpadded
  unsigned short* Bs = smem + 4096;            // [128][32]
  int tid = threadIdx.x;
  int wave = tid >> 6, lane = tid & 63;
  int quad = lane >> 4, l16 = lane & 15;
  int wm = wave >> 1, wn = wave & 1;
  int m0 = blockIdx.y * 128, n0 = blockIdx.x * 128;

  int srow = wave * 32 + (lane >> 2);
  int sch = (lane & 3) * 8;
  const unsigned short* Ab = A + (size_t)(m0 + srow) * K + sch;
  const unsigned short* Bb = Bw + (size_t)(n0 + srow) * K + sch;
  unsigned short* AsW = &As[wave * 32 * 32];
  unsigned short* BsW = &Bs[wave * 32 * 32];

  floatx4 acc[4][4];
  for (int i = 0; i < 4; ++i)
    for (int j = 0; j < 4; ++j) acc[i][j] = (floatx4)0.0f;

  for (int k0 = 0; k0 < K; k0 += 32) {
    __syncthreads();
    glds16(Ab + k0, AsW);
    glds16(Ab + k0 + 16 * K, AsW + 512);
    glds16(Bb + k0, BsW);
    glds16(Bb + k0 + 16 * K, BsW + 512);
    __builtin_amdgcn_s_waitcnt(0x0070);   // vmcnt(0) + lgkmcnt(0)
    __syncthreads();
    short8 af[4], bfr[4];
    for (int mt = 0; mt < 4; ++mt)
      af[mt] = *(const short8*)&As[(wm * 64 + mt * 16 + l16) * 32 + quad * 8];
    for (int nt = 0; nt < 4; ++nt)
      bfr[nt] = *(const short8*)&Bs[(wn * 64 + nt * 16 + l16) * 32 + quad * 8];
    for (int mt = 0; mt < 4; ++mt)
      for (int nt = 0; nt < 4; ++nt)
        acc[mt][nt] = __builtin_amdgcn_mfma_f32_16x16x32_bf16(af[mt], bfr[nt], acc[mt][nt], 0, 0, 0);
  }

  int tt = n0 % 384;        // 0 => QK tile; 128/256 => V tile
  int h = n0 / 384;
  __syncthreads();

  if (tt == 0) {
    for (int nt = 0; nt < 4; ++nt) {
      int o = n0 + wn * 64 + nt * 16 + l16;
      float sc = gamma[o] * rsqrtf(var[o] + 1e-5f);
      float bb = beta[o] - mean[o] * sc;
      if (wn == 0) { sc *= 0.125f; bb *= 0.125f; }
      int jl = wn * 64 + nt * 16 + l16;
      for (int mt = 0; mt < 4; ++mt)
        for (int r = 0; r < 4; ++r) {
          int ml = wm * 64 + mt * 16 + quad * 4 + r;
          smem[ml * OSTR + jl] = f2bf(acc[mt][nt][r] * sc + bb);
        }
    }
    __syncthreads();
    for (int i = 0; i < 8; ++i) {
      int c = i * 256 + tid;
      int ml = c >> 4, jc = c & 15;
      int m = m0 + ml;
      int b = m / 784, n = m - b * 784;
      uint4 v = *(uint4*)&smem[ml * OSTR + jc * 8];
      int j = jc * 8;
      if (j < 64) *(uint4*)&qo[(((size_t)b * NH + h) * Nseq + n) * KD + j] = v;
      else        *(uint4*)&ko[(((size_t)b * NH + h) * Nseq + n) * KD + (j - 64)] = v;
    }
  } else {
    for (int nt = 0; nt < 4; ++nt) {
      int o = n0 + wn * 64 + nt * 16 + l16;
      float sc = gamma[o] * rsqrtf(var[o] + 1e-5f);
      float bb = beta[o] - mean[o] * sc;
      int cl = wn * 64 + nt * 16 + l16;
      for (int mt = 0; mt < 4; ++mt)
        for (int r = 0; r < 4; ++r) {
          int ml = wm * 64 + mt * 16 + quad * 4 + r;
          smem[cl * OSTR + ml] = f2bf(acc[mt][nt][r] * sc + bb);
        }
    }
    __syncthreads();
    int cbase = tt - 128;
    for (int i = 0; i < 8; ++i) {
      int c = i * 256 + tid;
      int cl = c >> 4, mc = c & 15;
      int m = m0 + mc * 8;
      int b = m / 784, n = m - b * 784;
      uint4 v = *(uint4*)&smem[cl * OSTR + mc * 8];
      *(uint4*)&vto[(((size_t)b * NH + h) * VD + cbase + cl) * Nseq + n] = v;
    }
  }
}

// ---------------- K2: flash attention, glds pipeline + S^T softmax ----------------
// S^T = mfma(kf, qf): D[j=quad*4+r][i=l16] -> lane's 4 values are CONSECUTIVE j.
// bias_idxs is symmetric => bias tile [i][j] serves the transposed access as
// 1 ds_read_b64 per jt; P transposes to A-layout as 1 packed ds_write_b64 per jt.
// PV fragments are bit-identical to the non-transposed version (A/B lane maps match).
__global__ __launch_bounds__(256, 2) void attn_kernel(
    const unsigned short* __restrict__ qb,   // [bh][784][64] (pre-scaled by 1/8)
    const unsigned short* __restrict__ kb,   // [bh][784][64]
    const unsigned short* __restrict__ vtb,  // [bh][256][784]
    const unsigned short* __restrict__ bias_tab, // [8][784][784] bf16
    unsigned short* __restrict__ U)          // [16*784*2048] bf16 (post-SiLU)
{
  __shared__ unsigned short vt_lds[2 * 128 * 64];  // 32 KB: V^T half-tile, dbuf, swizzled
  __shared__ unsigned short k_lds[2 * 64 * 64];    // 16 KB: K tile, dbuf, swizzled
  __shared__ unsigned short bs_lds[2 * 64 * 64];   // 16 KB: bias tile [i][j], dbuf, swizzled
  __shared__ unsigned short ps_lds[4 * 16 * 64];   //  8 KB: per-wave P strip, swizzled
  int tid = threadIdx.x;
  int wave = tid >> 6, lane = tid & 63;
  int quad = lane >> 4, l16 = lane & 15;

  int L = blockIdx.x;
  int xcd = L & 7;
  int s = L >> 3;
  int vh = s & 1;                  // which half of VD
  int s2 = s >> 1;
  int qt = s2 % 13;
  int bh = (s2 / 13) * 8 + xcd;    // bh % 8 == h == xcd
  int b = bh >> 3, h = bh & 7;
  int row_base = qt * 64 + wave * 16;

  const unsigned short* brow = bias_tab + (size_t)h * NN;

  int lc = lane >> 3;              // 0..7 (row-sub for glds)
  int lch = (lane & 7) ^ lc;       // swizzled 16B chunk this lane fetches
  int sw = l16 & 7;                // read-side swizzle key

  const unsigned short* vsrc[4];
#pragma unroll
  for (int t = 0; t < 4; ++t)
    vsrc[t] = vtb + ((size_t)bh * VD + vh * 128 + wave * 32 + t * 8 + lc) * Nseq + lch * 8;
  const unsigned short* ksrc[2];
#pragma unroll
  for (int t = 0; t < 2; ++t)
    ksrc[t] = kb + (size_t)bh * (Nseq * KD) + (wave * 16 + t * 8 + lc) * KD + lch * 8;
  const unsigned short* bsrc[2];
#pragma unroll
  for (int t = 0; t < 2; ++t) {
    int ig = qt * 64 + wave * 16 + t * 8 + lc;
    if (ig > Nseq - 1) ig = Nseq - 1;   // clamp dead rows
    bsrc[t] = brow + (size_t)ig * Nseq + lch * 8;
  }

  // ---- prologue: issue tile 0 (8 glds) ----
#pragma unroll
  for (int t = 0; t < 4; ++t)
    glds16(vsrc[t], &vt_lds[(wave * 4 + t) * 512]);
#pragma unroll
  for (int t = 0; t < 2; ++t)
    glds16(ksrc[t], &k_lds[(wave * 2 + t) * 512]);
#pragma unroll
  for (int t = 0; t < 2; ++t)
    glds16(bsrc[t], &bs_lds[(wave * 2 + t) * 512]);

  // Q fragments (B-operand; same lane map as A): rows row_base+l16
  short8 qf[2];
  {
    int qrow = row_base + l16;   // OOB (qt=12) reads land in ko region: benign, masked rows
    const unsigned short* qp = qb + ((size_t)bh * Nseq + qrow) * KD;
    qf[0] = *(const short8*)(qp + quad * 8);
    qf[1] = *(const short8*)(qp + 32 + quad * 8);
  }

  float lsum = 0.0f;
  floatx4 oacc[8];
#pragma unroll
  for (int ct = 0; ct < 8; ++ct) oacc[ct] = (floatx4)0.0f;

  unsigned short* psW = &ps_lds[wave * 1024];

  for (int kt = 0; kt < 13; ++kt) {
    int cur = kt & 1;
    int nb = cur ^ 1;
    __builtin_amdgcn_s_waitcnt(0xC07F);   // lgkmcnt(0) only
    __builtin_amdgcn_s_barrier();

    int ktn = kt + 1; if (ktn >= 13) ktn = 0;
#pragma unroll
    for (int t = 0; t < 4; ++t)
      glds16(vsrc[t] + ktn * 64, &vt_lds[nb * 8192 + (wave * 4 + t) * 512]);
#pragma unroll
    for (int t = 0; t < 2; ++t)
      glds16(ksrc[t] + (size_t)ktn * 4096, &k_lds[nb * 4096 + (wave * 2 + t) * 512]);
#pragma unroll
    for (int t = 0; t < 2; ++t)
      glds16(bsrc[t] + ktn * 64, &bs_lds[nb * 4096 + (wave * 2 + t) * 512]);

    __builtin_amdgcn_s_waitcnt(0x0F78);   // vmcnt(8): tile kt landed, kt+1 in flight
    __builtin_amdgcn_s_barrier();

    const unsigned short* kbuf = &k_lds[cur * 4096];
    const unsigned short* vbuf = &vt_lds[cur * 8192];
    const unsigned short* bbuf = &bs_lds[cur * 4096];

    // S^T = K Q^T
    floatx4 st[4];
#pragma unroll
    for (int jt = 0; jt < 4; ++jt) {
      int row = jt * 16 + l16;
      short8 kf0 = *(const short8*)&kbuf[row * 64 + (quad ^ sw) * 8];
      short8 kf1 = *(const short8*)&kbuf[row * 64 + ((quad + 4) ^ sw) * 8];
      st[jt] = (floatx4)0.0f;
      st[jt] = __builtin_amdgcn_mfma_f32_16x16x32_bf16(kf0, qf[0], st[jt], 0, 0, 0);
      st[jt] = __builtin_amdgcn_mfma_f32_16x16x32_bf16(kf1, qf[1], st[jt], 0, 0, 0);
    }

    // bias (b64) + no-max softmax + packed P write (b64)
    bool tail = (kt == 12);
#pragma unroll
    for (int jt = 0; jt < 4; ++jt) {
      int ch = ((jt << 1) + (quad >> 1)) ^ sw;
      int half = (quad & 1) * 4;
      ushort4 bv = *(const ushort4*)&bbuf[(wave * 16 + l16) * 64 + ch * 8 + half];
      float p0 = EXP2((st[jt][0] + bf2f(bv.x)) * 1.44269504f);
      float p1 = EXP2((st[jt][1] + bf2f(bv.y)) * 1.44269504f);
      float p2 = EXP2((st[jt][2] + bf2f(bv.z)) * 1.44269504f);
      float p3 = EXP2((st[jt][3] + bf2f(bv.w)) * 1.44269504f);
      if (tail && jt > 0) { p0 = 0.0f; p1 = 0.0f; p2 = 0.0f; p3 = 0.0f; }
      lsum += (p0 + p1) + (p2 + p3);
      unsigned lo = (unsigned)f2bf(p0) | ((unsigned)f2bf(p1) << 16);
      unsigned hi = (unsigned)f2bf(p2) | ((unsigned)f2bf(p3) << 16);
      *(uint2*)&psW[l16 * 64 + ch * 8 + half] = make_uint2(lo, hi);
    }

    // O += P V
#pragma unroll
    for (int ks = 0; ks < 2; ++ks) {
      short8 pf = *(const short8*)&psW[l16 * 64 + ((ks * 4 + quad) ^ sw) * 8];
#pragma unroll
      for (int ct = 0; ct < 8; ++ct) {
        int c = ct * 16 + l16;
        short8 vf = *(const short8*)&vbuf[c * 64 + ((ks * 4 + quad) ^ sw) * 8];
        oacc[ct] = __builtin_amdgcn_mfma_f32_16x16x32_bf16(pf, vf, oacc[ct], 0, 0, 0);
      }
    }
  }

  // drain remaining async glds before LDS goes out of scope
  __builtin_amdgcn_s_waitcnt(0x0070);

  // epilogue: reduce lsum over the 4 quads, redistribute to acc rows, SiLU, write
  float tot = lsum;
  tot += __shfl_xor(tot, 16);
  tot += __shfl_xor(tot, 32);
  float inv[4];
#pragma unroll
  for (int r = 0; r < 4; ++r) {
    float lr = __shfl(tot, (lane & 48) | (quad * 4 + r));
    inv[r] = 1.0f / lr;
  }
#pragma unroll
  for (int r = 0; r < 4; ++r) {
    int ig = row_base + quad * 4 + r;
    if (ig >= Nseq) continue;
    size_t base = ((size_t)b * Nseq + ig) * HV + h * VD + vh * 128;
#pragma unroll
    for (int ct = 0; ct < 8; ++ct) {
      float u = oacc[ct][r] * inv[r];
      float sg = 1.0f / (1.0f + EXP2(-u * 1.44269504f));
      U[base + ct * 16 + l16] = f2bf(u * sg);
    }
  }
}

// ---------------- K3: proj GEMM (glds staging, operand-swapped) + BN ----------------
__global__ __launch_bounds__(256, 2) void proj_gemm_kernel(
    const unsigned short* __restrict__ Ubuf,  // [12544][2048]
    const unsigned short* __restrict__ Wp,    // [512][2048]
    const float* __restrict__ gamma, const float* __restrict__ beta,
    const float* __restrict__ mean,  const float* __restrict__ var,
    float* __restrict__ out)                  // [12544][512]
{
  const int K = HV;
  __shared__ unsigned short As[128 * 32];   // wp rows (o), unpadded
  __shared__ unsigned short Bs[128 * 32];   // Ub rows (m), unpadded
  int tid = threadIdx.x;
  int wave = tid >> 6, lane = tid & 63;
  int quad = lane >> 4, l16 = lane & 15;
  int wm = wave >> 1, wn = wave & 1;
  int o0 = blockIdx.y * 128, mB = blockIdx.x * 128;

  int srow = wave * 32 + (lane >> 2);
  int sch = (lane & 3) * 8;
  const unsigned short* Ab = Wp + (size_t)(o0 + srow) * K + sch;
  const unsigned short* Bb = Ubuf + (size_t)(mB + srow) * K + sch;
  unsigned short* AsW = &As[wave * 32 * 32];
  unsigned short* BsW = &Bs[wave * 32 * 32];

  floatx4 acc[4][4];
  for (int i = 0; i < 4; ++i)
    for (int j = 0; j < 4; ++j) acc[i][j] = (floatx4)0.0f;

  for (int k0 = 0; k0 < K; k0 += 32) {
    __syncthreads();
    glds16(Ab + k0, AsW);
    glds16(Ab + k0 + 16 * K, AsW + 512);
    glds16(Bb + k0, BsW);
    glds16(Bb + k0 + 16 * K, BsW + 512);
    __builtin_amdgcn_s_waitcnt(0x0070);
    __syncthreads();
    short8 af[4], bfr[4];
    for (int mt = 0; mt < 4; ++mt)
      af[mt] = *(const short8*)&As[(wm * 64 + mt * 16 + l16) * 32 + quad * 8];
    for (int nt = 0; nt < 4; ++nt)
      bfr[nt] = *(const short8*)&Bs[(wn * 64 + nt * 16 + l16) * 32 + quad * 8];
    for (int mt = 0; mt < 4; ++mt)
      for (int nt = 0; nt < 4; ++nt)
        acc[mt][nt] = __builtin_amdgcn_mfma_f32_16x16x32_bf16(af[mt], bfr[nt], acc[mt][nt], 0, 0, 0);
  }

  for (int mt = 0; mt < 4; ++mt) {
    int ob = o0 + wm * 64 + mt * 16 + quad * 4;
    float4 g = *(const float4*)&gamma[ob];
    float4 vr = *(const float4*)&var[ob];
    float4 mn = *(const float4*)&mean[ob];
    float4 bt = *(const float4*)&beta[ob];
    float sc0 = g.x * rsqrtf(vr.x + 1e-5f), bb0 = bt.x - mn.x * sc0;
    float sc1 = g.y * rsqrtf(vr.y + 1e-5f), bb1 = bt.y - mn.y * sc1;
    float sc2 = g.z * rsqrtf(vr.z + 1e-5f), bb2 = bt.z - mn.z * sc2;
    float sc3 = g.w * rsqrtf(vr.w + 1e-5f), bb3 = bt.w - mn.w * sc3;
    for (int nt = 0; nt < 4; ++nt) {
      int m = mB + wn * 64 + nt * 16 + l16;
      float4 v;
      v.x = acc[mt][nt][0] * sc0 + bb0;
      v.y = acc[mt][nt][1] * sc1 + bb1;
      v.z = acc[mt][nt][2] * sc2 + bb2;
      v.w = acc[mt][nt][3] * sc3 + bb3;
      *(float4*)&out[(size_t)m * DIM + ob] = v;
    }
  }
}

// ---------------- launch ----------------
extern "C" void kernel_launch(void* const* d_in, const int* in_sizes, int n_in,
                              void* d_out, int out_size, void* d_ws, size_t ws_size,
                              hipStream_t stream) {
  const float* x          = (const float*)d_in[0];
  const float* qkv_w      = (const float*)d_in[1];
  const float* qkv_gamma  = (const float*)d_in[2];
  const float* qkv_beta   = (const float*)d_in[3];
  const float* qkv_mean   = (const float*)d_in[4];
  const float* qkv_var    = (const float*)d_in[5];
  const float* att_biases = (const float*)d_in[6];
  const float* proj_w     = (const float*)d_in[7];
  const float* proj_gamma = (const float*)d_in[8];
  const float* proj_beta  = (const float*)d_in[9];
  const float* proj_mean  = (const float*)d_in[10];
  const float* proj_var   = (const float*)d_in[11];
  const int*   bias_idxs  = (const int*)d_in[12];
  float* out = (float*)d_out;

  char* ws = (char*)d_ws;
  unsigned short* xb  = (unsigned short*)(ws);                 // 12544*512 (12.85 MB)
  unsigned short* bias_tab = (unsigned short*)(ws);            // 8*784*784 bf16 — aliases xb (dead after qkv_gemm)
  unsigned short* wq  = (unsigned short*)(ws + 12845056);      // 3072*512
  unsigned short* wp  = (unsigned short*)(ws + 15990784);      // 512*2048
  unsigned short* qo  = (unsigned short*)(ws + 18087936);      // 16*8*784*64
  unsigned short* ko  = (unsigned short*)(ws + 30932992);      // 16*8*784*64
  unsigned short* vto = (unsigned short*)(ws + 43778048);      // 16*8*256*784
  unsigned short* Ub  = (unsigned short*)(ws + 95158272);      // 12544*2048
  // total: 146538496 bytes

  {
    int n4 = N4X + N4Q + N4P;
    cvt_all_kernel<<<(n4 + 255) / 256, 256, 0, stream>>>(x, qkv_w, proj_w, xb, wq, wp);
  }

  qkv_gemm_kernel<<<dim3(QKV_OUT / 128, (Bsz * Nseq) / 128), 256, 0, stream>>>(
      xb, wq, qkv_gamma, qkv_beta, qkv_mean, qkv_var, qo, ko, vto);

  bias_pre_kernel<<<(NN + 255) / 256, 256, 0, stream>>>(att_biases, bias_idxs, bias_tab);

  attn_kernel<<<13 * 2 * Bsz * NH, 256, 0, stream>>>(qo, ko, vto, bias_tab, Ub);

  proj_gemm_kernel<<<dim3((Bsz * Nseq) / 128, DIM / 128), 256, 0, stream>>>(
      Ub, wp, proj_gamma, proj_beta, proj_mean, proj_var, out);
}

// Round 7
// 337.752 us; speedup vs baseline: 3.2208x; 1.0844x over previous
//
#include <hip/hip_runtime.h>

// Problem constants
#define Bsz 16
#define Nseq 784
#define DIM 512
#define NH 8
#define KD 64
#define VD 256
#define QKV_OUT 3072   // (2*64+256)*8
#define HV 2048        // NH*VD
#define NN 614656      // 784*784

typedef __attribute__((ext_vector_type(8))) short short8;
typedef __attribute__((ext_vector_type(4))) float floatx4;

#define OSTR 136  // LDS row stride for qkv epilogue tile (bf16): 272B, 16B-aligned

#if __has_builtin(__builtin_amdgcn_exp2f)
#define EXP2(x) __builtin_amdgcn_exp2f(x)
#else
#define EXP2(x) exp2f(x)
#endif

__device__ __forceinline__ unsigned short f2bf(float f) {
  union { float f; unsigned u; } v; v.f = f;
  unsigned r = v.u + 0x7fffu + ((v.u >> 16) & 1u);
  return (unsigned short)(r >> 16);
}
__device__ __forceinline__ float bf2f(unsigned short u) {
  union { unsigned u; float f; } v; v.u = ((unsigned)u) << 16;
  return v.f;
}

// async global->LDS, 16B per lane; LDS dst = wave-uniform base + lane*16
__device__ __forceinline__ void glds16(const unsigned short* g, unsigned short* l) {
  __builtin_amdgcn_global_load_lds(
      (const __attribute__((address_space(1))) void*)g,
      (__attribute__((address_space(3))) void*)l, 16, 0, 0);
}

// ---------------- K0: fused fp32 -> bf16 convert (x, qkv_w, proj_w) ----------------
#define N4X 1605632   // x float4s
#define N4Q 393216    // qkv_w float4s
#define N4P 262144    // proj_w float4s
__global__ void cvt_all_kernel(const float* __restrict__ x,
                               const float* __restrict__ qw,
                               const float* __restrict__ pw,
                               unsigned short* __restrict__ xb,
                               unsigned short* __restrict__ wq,
                               unsigned short* __restrict__ wp) {
  int i = blockIdx.x * 256 + threadIdx.x;
  const float4* s; ushort4* d; int off;
  if (i < N4X)              { s = (const float4*)x;  d = (ushort4*)xb; off = i; }
  else if (i < N4X + N4Q)   { s = (const float4*)qw; d = (ushort4*)wq; off = i - N4X; }
  else if (i < N4X + N4Q + N4P) { s = (const float4*)pw; d = (ushort4*)wp; off = i - N4X - N4Q; }
  else return;
  float4 v = s[off];
  ushort4 o;
  o.x = f2bf(v.x); o.y = f2bf(v.y); o.z = f2bf(v.z); o.w = f2bf(v.w);
  d[off] = o;
}

// ---------------- K0b: materialize bias table [8][784][784] bf16 ----------------
__global__ void bias_pre_kernel(const float* __restrict__ biases,
                                const int* __restrict__ bias_idxs,
                                unsigned short* __restrict__ bias_tab) {
  int t = blockIdx.x * 256 + threadIdx.x;
  if (t >= NN) return;
  int idx = bias_idxs[t];
  for (int h = 0; h < NH; ++h)
    bias_tab[(size_t)h * NN + t] = f2bf(biases[h * Nseq + idx]);
}

// ---------------- K1: QKV GEMM (dbuf glds pipeline) + BN + LDS-staged scatter ----------------
__global__ __launch_bounds__(256, 2) void qkv_gemm_kernel(
    const unsigned short* __restrict__ A,
    const unsigned short* __restrict__ Bw,
    const float* __restrict__ gamma, const float* __restrict__ beta,
    const float* __restrict__ mean,  const float* __restrict__ var,
    unsigned short* __restrict__ qo,   // [B,H,N,64] (pre-scaled by 0.125)
    unsigned short* __restrict__ ko,   // [B,H,N,64]
    unsigned short* __restrict__ vto)  // [B,H,256,N]
{
  const int K = DIM;
  __shared__ unsigned short smem[128 * OSTR];  // 34816B; staging dbuf uses first 32KB
  // staging carve: As[2][128*32], Bs[2][128*32]
  int tid = threadIdx.x;
  int wave = tid >> 6, lane = tid & 63;
  int quad = lane >> 4, l16 = lane & 15;
  int wm = wave >> 1, wn = wave & 1;
  int m0 = blockIdx.y * 128, n0 = blockIdx.x * 128;

  int srow = wave * 32 + (lane >> 2);
  int sch = (lane & 3) * 8;
  const unsigned short* Ab = A + (size_t)(m0 + srow) * K + sch;
  const unsigned short* Bb = Bw + (size_t)(n0 + srow) * K + sch;
  unsigned short* AsW = &smem[wave * 1024];          // within As buf
  unsigned short* BsW = &smem[4096 + wave * 1024];   // within Bs buf

  floatx4 acc[4][4];
  for (int i = 0; i < 4; ++i)
    for (int j = 0; j < 4; ++j) acc[i][j] = (floatx4)0.0f;

  // prologue: stage k-step 0 into buf 0
  glds16(Ab, AsW);
  glds16(Ab + 16 * K, AsW + 512);
  glds16(Bb, BsW);
  glds16(Bb + 16 * K, BsW + 512);

  for (int k = 0; k < 16; ++k) {
    int cur = k & 1, nb = cur ^ 1;
    __builtin_amdgcn_s_waitcnt(0xC07F);   // lgkmcnt(0) only
    __builtin_amdgcn_s_barrier();
    int k0n = ((k + 1) & 15) * 32;        // wrap keeps vmcnt uniform
    glds16(Ab + k0n, AsW + nb * 8192);
    glds16(Ab + k0n + 16 * K, AsW + nb * 8192 + 512);
    glds16(Bb + k0n, BsW + nb * 8192);
    glds16(Bb + k0n + 16 * K, BsW + nb * 8192 + 512);
    __builtin_amdgcn_s_waitcnt(0x0F74);   // vmcnt(4): this k landed, k+1 in flight
    __builtin_amdgcn_s_barrier();

    const unsigned short* As = &smem[cur * 8192];
    const unsigned short* Bs = &smem[4096 + cur * 8192];
    short8 af[4], bfr[4];
    for (int mt = 0; mt < 4; ++mt)
      af[mt] = *(const short8*)&As[(wm * 64 + mt * 16 + l16) * 32 + quad * 8];
    for (int nt = 0; nt < 4; ++nt)
      bfr[nt] = *(const short8*)&Bs[(wn * 64 + nt * 16 + l16) * 32 + quad * 8];
    for (int mt = 0; mt < 4; ++mt)
      for (int nt = 0; nt < 4; ++nt)
        acc[mt][nt] = __builtin_amdgcn_mfma_f32_16x16x32_bf16(af[mt], bfr[nt], acc[mt][nt], 0, 0, 0);
  }

  int tt = n0 % 384;        // 0 => QK tile; 128/256 => V tile
  int h = n0 / 384;
  __builtin_amdgcn_s_waitcnt(0x0070);   // drain wrapped prefetch before smem reuse
  __syncthreads();

  if (tt == 0) {
    for (int nt = 0; nt < 4; ++nt) {
      int o = n0 + wn * 64 + nt * 16 + l16;
      float sc = gamma[o] * rsqrtf(var[o] + 1e-5f);
      float bb = beta[o] - mean[o] * sc;
      if (wn == 0) { sc *= 0.125f; bb *= 0.125f; }
      int jl = wn * 64 + nt * 16 + l16;
      for (int mt = 0; mt < 4; ++mt)
        for (int r = 0; r < 4; ++r) {
          int ml = wm * 64 + mt * 16 + quad * 4 + r;
          smem[ml * OSTR + jl] = f2bf(acc[mt][nt][r] * sc + bb);
        }
    }
    __syncthreads();
    for (int i = 0; i < 8; ++i) {
      int c = i * 256 + tid;
      int ml = c >> 4, jc = c & 15;
      int m = m0 + ml;
      int b = m / 784, n = m - b * 784;
      uint4 v = *(uint4*)&smem[ml * OSTR + jc * 8];
      int j = jc * 8;
      if (j < 64) *(uint4*)&qo[(((size_t)b * NH + h) * Nseq + n) * KD + j] = v;
      else        *(uint4*)&ko[(((size_t)b * NH + h) * Nseq + n) * KD + (j - 64)] = v;
    }
  } else {
    for (int nt = 0; nt < 4; ++nt) {
      int o = n0 + wn * 64 + nt * 16 + l16;
      float sc = gamma[o] * rsqrtf(var[o] + 1e-5f);
      float bb = beta[o] - mean[o] * sc;
      int cl = wn * 64 + nt * 16 + l16;
      for (int mt = 0; mt < 4; ++mt)
        for (int r = 0; r < 4; ++r) {
          int ml = wm * 64 + mt * 16 + quad * 4 + r;
          smem[cl * OSTR + ml] = f2bf(acc[mt][nt][r] * sc + bb);
        }
    }
    __syncthreads();
    int cbase = tt - 128;
    for (int i = 0; i < 8; ++i) {
      int c = i * 256 + tid;
      int cl = c >> 4, mc = c & 15;
      int m = m0 + mc * 8;
      int b = m / 784, n = m - b * 784;
      uint4 v = *(uint4*)&smem[cl * OSTR + mc * 8];
      *(uint4*)&vto[(((size_t)b * NH + h) * VD + cbase + cl) * Nseq + n] = v;
    }
  }
}

// ---------------- K2: flash attention, 8-wave blocks, 128 Q rows x 256 channels ----------------
// Dedup: one block per (qp, bh) stages K/V/bias ONCE for 128 Q rows and all 256
// V channels (round 6's vh split computed every S element twice and read K 26x).
// Same glds + vmcnt(7) + raw-barrier pipeline; S^T trick retained.
__global__ __launch_bounds__(512, 2) void attn_kernel(
    const unsigned short* __restrict__ qb,   // [bh][784][64] (pre-scaled by 1/8)
    const unsigned short* __restrict__ kb,   // [bh][784][64]
    const unsigned short* __restrict__ vtb,  // [bh][256][784]
    const unsigned short* __restrict__ bias_tab, // [8][784][784] bf16
    unsigned short* __restrict__ U)          // [16*784*2048] bf16 (post-SiLU)
{
  __shared__ unsigned short vt_lds[2 * 256 * 64];  // 64 KB, dbuf, swizzled
  __shared__ unsigned short k_lds[2 * 64 * 64];    // 16 KB, dbuf, swizzled
  __shared__ unsigned short bs_lds[2 * 128 * 64];  // 32 KB, dbuf, swizzled
  __shared__ unsigned short ps_lds[8 * 16 * 64];   // 16 KB per-wave P strips
  int tid = threadIdx.x;
  int wave = tid >> 6, lane = tid & 63;
  int quad = lane >> 4, l16 = lane & 15;

  int L = blockIdx.x;
  int xcd = L & 7;
  int s = L >> 3;            // 0..111
  int qp = s % 7;            // 128-row Q group
  int bg = s / 7;            // batch
  int bh = bg * 8 + xcd;     // bh % 8 == h == xcd (head-bias L2 locality)
  int b = bg, h = xcd;
  int row_base = qp * 128 + wave * 16;

  const unsigned short* brow = bias_tab + (size_t)h * NN;

  int lc = lane >> 3;              // 0..7 (row-sub for glds)
  int lch = (lane & 7) ^ lc;       // swizzled 16B chunk this lane fetches
  int sw = l16 & 7;                // read-side swizzle key

  const unsigned short* vsrc[4];
#pragma unroll
  for (int t = 0; t < 4; ++t)
    vsrc[t] = vtb + ((size_t)bh * VD + t * 64 + wave * 8 + lc) * Nseq + lch * 8;
  const unsigned short* ksrc =
      kb + (size_t)bh * (Nseq * KD) + (wave * 8 + lc) * KD + lch * 8;
  const unsigned short* bsrc[2];
#pragma unroll
  for (int t = 0; t < 2; ++t) {
    int ig = qp * 128 + t * 64 + wave * 8 + lc;
    if (ig > Nseq - 1) ig = Nseq - 1;   // clamp dead rows
    bsrc[t] = brow + (size_t)ig * Nseq + lch * 8;
  }

  // Q fragments first (oldest vm ops; rows beyond 784 read into ko region: benign)
  short8 qf[2];
  {
    int qrow = row_base + l16;
    const unsigned short* qp_ = qb + ((size_t)bh * Nseq + qrow) * KD;
    qf[0] = *(const short8*)(qp_ + quad * 8);
    qf[1] = *(const short8*)(qp_ + 32 + quad * 8);
  }

  // ---- prologue: issue tile 0 (7 glds/lane) ----
#pragma unroll
  for (int t = 0; t < 4; ++t)
    glds16(vsrc[t], &vt_lds[(t * 64 + wave * 8) * 64]);
  glds16(ksrc, &k_lds[wave * 512]);
#pragma unroll
  for (int t = 0; t < 2; ++t)
    glds16(bsrc[t], &bs_lds[(t * 64 + wave * 8) * 64]);

  float lsum = 0.0f;
  floatx4 oacc[16];
#pragma unroll
  for (int ct = 0; ct < 16; ++ct) oacc[ct] = (floatx4)0.0f;

  unsigned short* psW = &ps_lds[wave * 1024];

  for (int kt = 0; kt < 13; ++kt) {
    int cur = kt & 1;
    int nb = cur ^ 1;
    __builtin_amdgcn_s_waitcnt(0xC07F);   // lgkmcnt(0) only
    __builtin_amdgcn_s_barrier();

    int ktn = kt + 1; if (ktn >= 13) ktn = 0;   // wrap keeps vmcnt uniform
#pragma unroll
    for (int t = 0; t < 4; ++t)
      glds16(vsrc[t] + ktn * 64, &vt_lds[nb * 16384 + (t * 64 + wave * 8) * 64]);
    glds16(ksrc + (size_t)ktn * 4096, &k_lds[nb * 4096 + wave * 512]);
#pragma unroll
    for (int t = 0; t < 2; ++t)
      glds16(bsrc[t] + ktn * 64, &bs_lds[nb * 8192 + (t * 64 + wave * 8) * 64]);

    __builtin_amdgcn_s_waitcnt(0x0F77);   // vmcnt(7): tile kt landed, kt+1 in flight
    __builtin_amdgcn_s_barrier();

    const unsigned short* kbuf = &k_lds[cur * 4096];
    const unsigned short* vbuf = &vt_lds[cur * 16384];
    const unsigned short* bbuf = &bs_lds[cur * 8192];

    // S^T = K Q^T  (D[j=quad*4+r][i=l16])
    floatx4 st[4];
#pragma unroll
    for (int jt = 0; jt < 4; ++jt) {
      int row = jt * 16 + l16;
      short8 kf0 = *(const short8*)&kbuf[row * 64 + (quad ^ sw) * 8];
      short8 kf1 = *(const short8*)&kbuf[row * 64 + ((quad + 4) ^ sw) * 8];
      st[jt] = (floatx4)0.0f;
      st[jt] = __builtin_amdgcn_mfma_f32_16x16x32_bf16(kf0, qf[0], st[jt], 0, 0, 0);
      st[jt] = __builtin_amdgcn_mfma_f32_16x16x32_bf16(kf1, qf[1], st[jt], 0, 0, 0);
    }

    // bias (b64, symmetric table) + no-max softmax + packed P write (b64)
    bool tail = (kt == 12);
#pragma unroll
    for (int jt = 0; jt < 4; ++jt) {
      int ch = ((jt << 1) + (quad >> 1)) ^ sw;
      int half = (quad & 1) * 4;
      ushort4 bv = *(const ushort4*)&bbuf[(wave * 16 + l16) * 64 + ch * 8 + half];
      float p0 = EXP2((st[jt][0] + bf2f(bv.x)) * 1.44269504f);
      float p1 = EXP2((st[jt][1] + bf2f(bv.y)) * 1.44269504f);
      float p2 = EXP2((st[jt][2] + bf2f(bv.z)) * 1.44269504f);
      float p3 = EXP2((st[jt][3] + bf2f(bv.w)) * 1.44269504f);
      if (tail && jt > 0) { p0 = 0.0f; p1 = 0.0f; p2 = 0.0f; p3 = 0.0f; }
      lsum += (p0 + p1) + (p2 + p3);
      unsigned lo = (unsigned)f2bf(p0) | ((unsigned)f2bf(p1) << 16);
      unsigned hi = (unsigned)f2bf(p2) | ((unsigned)f2bf(p3) << 16);
      *(uint2*)&psW[l16 * 64 + ch * 8 + half] = make_uint2(lo, hi);
    }

    // O += P V : 16 col-tiles over all 256 channels
#pragma unroll
    for (int ks = 0; ks < 2; ++ks) {
      short8 pf = *(const short8*)&psW[l16 * 64 + ((ks * 4 + quad) ^ sw) * 8];
#pragma unroll
      for (int ct = 0; ct < 16; ++ct) {
        int c = ct * 16 + l16;
        short8 vf = *(const short8*)&vbuf[c * 64 + ((ks * 4 + quad) ^ sw) * 8];
        oacc[ct] = __builtin_amdgcn_mfma_f32_16x16x32_bf16(pf, vf, oacc[ct], 0, 0, 0);
      }
    }
  }

  // drain remaining async glds before LDS goes out of scope
  __builtin_amdgcn_s_waitcnt(0x0070);

  // epilogue: reduce lsum over quads, redistribute to acc rows, SiLU, write
  float tot = lsum;
  tot += __shfl_xor(tot, 16);
  tot += __shfl_xor(tot, 32);
  float inv[4];
#pragma unroll
  for (int r = 0; r < 4; ++r) {
    float lr = __shfl(tot, (lane & 48) | (quad * 4 + r));
    inv[r] = 1.0f / lr;
  }
#pragma unroll
  for (int r = 0; r < 4; ++r) {
    int ig = row_base + quad * 4 + r;
    if (ig >= Nseq) continue;
    size_t base = ((size_t)b * Nseq + ig) * HV + h * VD;
#pragma unroll
    for (int ct = 0; ct < 16; ++ct) {
      float u = oacc[ct][r] * inv[r];
      float sg = 1.0f / (1.0f + EXP2(-u * 1.44269504f));
      U[base + ct * 16 + l16] = f2bf(u * sg);
    }
  }
}

// ---------------- K3: proj GEMM (dbuf glds pipeline, operand-swapped) + BN ----------------
__global__ __launch_bounds__(256, 2) void proj_gemm_kernel(
    const unsigned short* __restrict__ Ubuf,  // [12544][2048]
    const unsigned short* __restrict__ Wp,    // [512][2048]
    const float* __restrict__ gamma, const float* __restrict__ beta,
    const float* __restrict__ mean,  const float* __restrict__ var,
    float* __restrict__ out)                  // [12544][512]
{
  const int K = HV;
  __shared__ unsigned short smem[16384];   // As[2][4096] + Bs[2][4096]
  int tid = threadIdx.x;
  int wave = tid >> 6, lane = tid & 63;
  int quad = lane >> 4, l16 = lane & 15;
  int wm = wave >> 1, wn = wave & 1;
  int o0 = blockIdx.y * 128, mB = blockIdx.x * 128;

  int srow = wave * 32 + (lane >> 2);
  int sch = (lane & 3) * 8;
  const unsigned short* Ab = Wp + (size_t)(o0 + srow) * K + sch;
  const unsigned short* Bb = Ubuf + (size_t)(mB + srow) * K + sch;
  unsigned short* AsW = &smem[wave * 1024];
  unsigned short* BsW = &smem[4096 + wave * 1024];

  floatx4 acc[4][4];
  for (int i = 0; i < 4; ++i)
    for (int j = 0; j < 4; ++j) acc[i][j] = (floatx4)0.0f;

  glds16(Ab, AsW);
  glds16(Ab + 16 * K, AsW + 512);
  glds16(Bb, BsW);
  glds16(Bb + 16 * K, BsW + 512);

  for (int k = 0; k < 64; ++k) {
    int cur = k & 1, nb = cur ^ 1;
    __builtin_amdgcn_s_waitcnt(0xC07F);
    __builtin_amdgcn_s_barrier();
    int k0n = ((k + 1) & 63) * 32;
    glds16(Ab + k0n, AsW + nb * 8192);
    glds16(Ab + k0n + 16 * K, AsW + nb * 8192 + 512);
    glds16(Bb + k0n, BsW + nb * 8192);
    glds16(Bb + k0n + 16 * K, BsW + nb * 8192 + 512);
    __builtin_amdgcn_s_waitcnt(0x0F74);   // vmcnt(4)
    __builtin_amdgcn_s_barrier();

    const unsigned short* As = &smem[cur * 8192];
    const unsigned short* Bs = &smem[4096 + cur * 8192];
    short8 af[4], bfr[4];
    for (int mt = 0; mt < 4; ++mt)
      af[mt] = *(const short8*)&As[(wm * 64 + mt * 16 + l16) * 32 + quad * 8];
    for (int nt = 0; nt < 4; ++nt)
      bfr[nt] = *(const short8*)&Bs[(wn * 64 + nt * 16 + l16) * 32 + quad * 8];
    for (int mt = 0; mt < 4; ++mt)
      for (int nt = 0; nt < 4; ++nt)
        acc[mt][nt] = __builtin_amdgcn_mfma_f32_16x16x32_bf16(af[mt], bfr[nt], acc[mt][nt], 0, 0, 0);
  }
  __builtin_amdgcn_s_waitcnt(0x0070);   // drain wrapped prefetch

  for (int mt = 0; mt < 4; ++mt) {
    int ob = o0 + wm * 64 + mt * 16 + quad * 4;
    float4 g = *(const float4*)&gamma[ob];
    float4 vr = *(const float4*)&var[ob];
    float4 mn = *(const float4*)&mean[ob];
    float4 bt = *(const float4*)&beta[ob];
    float sc0 = g.x * rsqrtf(vr.x + 1e-5f), bb0 = bt.x - mn.x * sc0;
    float sc1 = g.y * rsqrtf(vr.y + 1e-5f), bb1 = bt.y - mn.y * sc1;
    float sc2 = g.z * rsqrtf(vr.z + 1e-5f), bb2 = bt.z - mn.z * sc2;
    float sc3 = g.w * rsqrtf(vr.w + 1e-5f), bb3 = bt.w - mn.w * sc3;
    for (int nt = 0; nt < 4; ++nt) {
      int m = mB + wn * 64 + nt * 16 + l16;
      float4 v;
      v.x = acc[mt][nt][0] * sc0 + bb0;
      v.y = acc[mt][nt][1] * sc1 + bb1;
      v.z = acc[mt][nt][2] * sc2 + bb2;
      v.w = acc[mt][nt][3] * sc3 + bb3;
      *(float4*)&out[(size_t)m * DIM + ob] = v;
    }
  }
}

// ---------------- launch ----------------
extern "C" void kernel_launch(void* const* d_in, const int* in_sizes, int n_in,
                              void* d_out, int out_size, void* d_ws, size_t ws_size,
                              hipStream_t stream) {
  const float* x          = (const float*)d_in[0];
  const float* qkv_w      = (const float*)d_in[1];
  const float* qkv_gamma  = (const float*)d_in[2];
  const float* qkv_beta   = (const float*)d_in[3];
  const float* qkv_mean   = (const float*)d_in[4];
  const float* qkv_var    = (const float*)d_in[5];
  const float* att_biases = (const float*)d_in[6];
  const float* proj_w     = (const float*)d_in[7];
  const float* proj_gamma = (const float*)d_in[8];
  const float* proj_beta  = (const float*)d_in[9];
  const float* proj_mean  = (const float*)d_in[10];
  const float* proj_var   = (const float*)d_in[11];
  const int*   bias_idxs  = (const int*)d_in[12];
  float* out = (float*)d_out;

  char* ws = (char*)d_ws;
  unsigned short* xb  = (unsigned short*)(ws);                 // 12544*512 (12.85 MB)
  unsigned short* bias_tab = (unsigned short*)(ws);            // 8*784*784 bf16 — aliases xb (dead after qkv_gemm)
  unsigned short* wq  = (unsigned short*)(ws + 12845056);      // 3072*512
  unsigned short* wp  = (unsigned short*)(ws + 15990784);      // 512*2048
  unsigned short* qo  = (unsigned short*)(ws + 18087936);      // 16*8*784*64
  unsigned short* ko  = (unsigned short*)(ws + 30932992);      // 16*8*784*64
  unsigned short* vto = (unsigned short*)(ws + 43778048);      // 16*8*256*784
  unsigned short* Ub  = (unsigned short*)(ws + 95158272);      // 12544*2048
  // total: 146538496 bytes

  {
    int n4 = N4X + N4Q + N4P;
    cvt_all_kernel<<<(n4 + 255) / 256, 256, 0, stream>>>(x, qkv_w, proj_w, xb, wq, wp);
  }

  qkv_gemm_kernel<<<dim3(QKV_OUT / 128, (Bsz * Nseq) / 128), 256, 0, stream>>>(
      xb, wq, qkv_gamma, qkv_beta, qkv_mean, qkv_var, qo, ko, vto);

  bias_pre_kernel<<<(NN + 255) / 256, 256, 0, stream>>>(att_biases, bias_idxs, bias_tab);

  attn_kernel<<<7 * Bsz * NH, 512, 0, stream>>>(qo, ko, vto, bias_tab, Ub);

  proj_gemm_kernel<<<dim3((Bsz * Nseq) / 128, DIM / 128), 256, 0, stream>>>(
      Ub, wp, proj_gamma, proj_beta, proj_mean, proj_var, out);
}